// Round 5
// baseline (2404.563 us; speedup 1.0000x reference)
//
#include <hip/hip_runtime.h>
#include <hip/hip_bf16.h>

// Problem constants (fixed by the reference)
constexpr int NE   = 100000;     // entities
constexpr int NZ   = 1600000;    // nnz (divisible by 256)
constexpr int NZH  = NZ / 2;
constexpr int NSB  = (NE + 1023) / 1024;   // 98 scan blocks
constexpr float EPSV = 1e-5f;

// f32 weight-scratch layout (element offsets)
constexpr int W1O = 0,     B1O = 3584,  W2O = 3616,  B2O = 17952, W3O = 18016,
              B3O = 32352, WPO = 32384, BPO = 32896, WLO = 32912, BLO = 33168,
              WTOT = 33184;

typedef __hip_bfloat16 bf16;
typedef __attribute__((ext_vector_type(8))) short short8v;   // 8 bf16 (4 VGPRs)
typedef __attribute__((ext_vector_type(4))) float f32x4;     // MFMA C/D
#define MFMA_B16(A_, B_, C_) __builtin_amdgcn_mfma_f32_16x16x32_bf16((A_), (B_), (C_), 0, 0, 0)
#define PARTNER(i_) (((i_) < NZH) ? (i_) + NZH : (i_) - NZH)

// ---------- helpers ----------
__device__ __forceinline__ float4 ld_bf4(const bf16* p) {
    uint2 u = *(const uint2*)p;
    float4 r;
    r.x = __uint_as_float(u.x << 16);
    r.y = __uint_as_float(u.x & 0xffff0000u);
    r.z = __uint_as_float(u.y << 16);
    r.w = __uint_as_float(u.y & 0xffff0000u);
    return r;
}
__device__ __forceinline__ void cv_bf8(uint4 u, float4& lo, float4& hi) {
    lo.x = __uint_as_float(u.x << 16); lo.y = __uint_as_float(u.x & 0xffff0000u);
    lo.z = __uint_as_float(u.y << 16); lo.w = __uint_as_float(u.y & 0xffff0000u);
    hi.x = __uint_as_float(u.z << 16); hi.y = __uint_as_float(u.z & 0xffff0000u);
    hi.z = __uint_as_float(u.w << 16); hi.w = __uint_as_float(u.w & 0xffff0000u);
}
__device__ __forceinline__ void ld_bf8v(const bf16* p, float4& lo, float4& hi) {
    cv_bf8(*(const uint4*)p, lo, hi);
}
__device__ __forceinline__ float2 ld_bf2(const bf16* p) {
    unsigned u = *(const unsigned*)p;
    float2 r;
    r.x = __uint_as_float(u << 16);
    r.y = __uint_as_float(u & 0xffff0000u);
    return r;
}
__device__ __forceinline__ void st_bf4(bf16* p, float4 v) {
    __hip_bfloat162 lo = __float22bfloat162_rn(make_float2(v.x, v.y));
    __hip_bfloat162 hi = __float22bfloat162_rn(make_float2(v.z, v.w));
    uint2 u;
    u.x = *reinterpret_cast<unsigned int*>(&lo);
    u.y = *reinterpret_cast<unsigned int*>(&hi);
    *(uint2*)p = u;
}
__device__ __forceinline__ void st_bf8(bf16* p, float4 a, float4 b) {
    __hip_bfloat162 p0 = __float22bfloat162_rn(make_float2(a.x, a.y));
    __hip_bfloat162 p1 = __float22bfloat162_rn(make_float2(a.z, a.w));
    __hip_bfloat162 p2 = __float22bfloat162_rn(make_float2(b.x, b.y));
    __hip_bfloat162 p3 = __float22bfloat162_rn(make_float2(b.z, b.w));
    uint4 u;
    u.x = *reinterpret_cast<unsigned int*>(&p0);
    u.y = *reinterpret_cast<unsigned int*>(&p1);
    u.z = *reinterpret_cast<unsigned int*>(&p2);
    u.w = *reinterpret_cast<unsigned int*>(&p3);
    *(uint4*)p = u;
}
__device__ __forceinline__ float fin1(float v) { return (fabsf(v) < 1e30f) ? v : 0.f; }
__device__ __forceinline__ float4 fin4(float4 v) {
    v.x = fin1(v.x); v.y = fin1(v.y); v.z = fin1(v.z); v.w = fin1(v.w);
    return v;
}
__device__ __forceinline__ float4 ld_x4(const void* p, int flag, size_t q4) {
    if (flag) return ld_bf4((const bf16*)p + q4 * 4);
    return *((const float4*)p + q4);
}
__device__ __forceinline__ float4 relu4s(float4 x, float4 a, float4 b, const float* c) {
    float4 r;
    r.x = fmaxf(x.x + a.x + b.x + c[0], 0.f);
    r.y = fmaxf(x.y + a.y + b.y + c[1], 0.f);
    r.z = fmaxf(x.z + a.z + b.z + c[2], 0.f);
    r.w = fmaxf(x.w + a.w + b.w + c[3], 0.f);
    return r;
}
// split 8 floats into bf16 hi + lo residual fragments
__device__ __forceinline__ void split8(const float* x, short8v& hi, short8v& lo) {
    #pragma unroll
    for (int i = 0; i < 8; i++) {
        bf16 h = __float2bfloat16(x[i]);
        float r = x[i] - __bfloat162float(h);
        bf16 l2 = __float2bfloat16(r);
        hi[i] = *reinterpret_cast<short*>(&h);
        lo[i] = *reinterpret_cast<short*>(&l2);
    }
}
#define BF2F(h) __bfloat162float(h)
#define ADD4(D_, A_) do { (D_).x += (A_).x; (D_).y += (A_).y; (D_).z += (A_).z; (D_).w += (A_).w; } while(0)
#define SQ4(D_, A_) do { (D_).x += (A_).x*(A_).x; (D_).y += (A_).y*(A_).y; \
                         (D_).z += (A_).z*(A_).z; (D_).w += (A_).w*(A_).w; } while(0)
#define FMA4S(D_, S_, W_) do { (D_).x += (S_)*(W_).x; (D_).y += (S_)*(W_).y; \
                               (D_).z += (S_)*(W_).z; (D_).w += (S_)*(W_).w; } while(0)

// ---------- dtype detection ----------
__global__ void k_detect(const unsigned* __restrict__ v, int* __restrict__ dflag) {
    int lane = threadIdx.x;
    unsigned w = v[lane * 7 + 1];
    unsigned b = (w >> 8) & 0xFFu;
    bool plausible = (b >= 0x36u && b <= 0x41u) || (b >= 0xB6u && b <= 0xC1u);
    unsigned long long m = __ballot(plausible);
    if (lane == 0) {
        dflag[0] = (__popcll(m) >= 32) ? 1 : 0;   // 1 = bf16, 0 = f32
        dflag[1] = 0;                              // perm-structure violation flag
    }
}

__global__ void k_convW(const void* W1, const void* b1, const void* W2, const void* b2,
                        const void* W3, const void* b3, const void* Wp, const void* bp,
                        const void* Wl, const void* bl, const int* __restrict__ dflag,
                        float* __restrict__ Wb) {
    int t = blockIdx.x * 256 + threadIdx.x;
    if (t >= WTOT) return;
    int flag = dflag[0];
    const void* src; int l;
    if      (t < B1O) { src = W1; l = t; }
    else if (t < W2O) { src = b1; l = t - B1O; }
    else if (t < B2O) { src = W2; l = t - W2O; }
    else if (t < W3O) { src = b2; l = t - B2O; }
    else if (t < B3O) { src = W3; l = t - W3O; }
    else if (t < WPO) { src = b3; l = t - B3O; }
    else if (t < BPO) { src = Wp; l = t - WPO; }
    else if (t < WLO) { src = bp; l = t - BPO; }
    else if (t < BLO) { src = Wl; l = t - WLO; }
    else              { src = bl; l = t - BLO; }
    float v = flag ? BF2F(((const bf16*)src)[l]) : ((const float*)src)[l];
    Wb[t] = fin1(v);
}

// ---------- shared small kernels ----------
__global__ void k_prep(float* misc) {              // rs0 = 1 (m0=0 via memset)
    int t = threadIdx.x;
    if (t < 64) misc[64 + t] = 1.0f;
}

__global__ void k_count(const int* __restrict__ row, int* __restrict__ cnt) {
    int i = blockIdx.x * 256 + threadIdx.x;
    atomicAdd(&cnt[row[i]], 1);
}

__global__ void k_invcnt(const int* __restrict__ cnt, float* __restrict__ invc) {
    int n = blockIdx.x * 256 + threadIdx.x;
    if (n < NE) invc[n] = 1.0f / (float)max(cnt[n], 1);
}

__global__ void k_tm(const void* __restrict__ xv, const int* __restrict__ dflag,
                     float* __restrict__ tmsum) {
    int flag = dflag[0];
    __shared__ float s[16];
    if (threadIdx.x < 16) s[threadIdx.x] = 0.f;
    __syncthreads();
    float4 acc = {0, 0, 0, 0};
    int q = (blockIdx.x * 256 + threadIdx.x) & 3;
    for (size_t i = (size_t)blockIdx.x * 256 + threadIdx.x; i < (size_t)NZ * 4;
         i += (size_t)gridDim.x * 256) {
        float4 v = fin4(ld_x4(xv, flag, i));
        ADD4(acc, v);
    }
    atomicAdd(&s[q * 4 + 0], acc.x); atomicAdd(&s[q * 4 + 1], acc.y);
    atomicAdd(&s[q * 4 + 2], acc.z); atomicAdd(&s[q * 4 + 3], acc.w);
    __syncthreads();
    if (threadIdx.x < 16) unsafeAtomicAdd(&tmsum[threadIdx.x], s[threadIdx.x]);
}

__global__ void k_const(const float* __restrict__ W, const float* __restrict__ bias,
                        const float* __restrict__ tmsum, int use_tm, float* __restrict__ c0,
                        int CIN, int COUT) {
    int co = threadIdx.x;
    if (co < COUT) {
        float v = bias[co];
        if (use_tm)
            for (int ci = 0; ci < CIN; ci++)
                v += tmsum[ci] * (1.0f / NZ) * W[(6 * CIN + ci) * COUT + co];
        c0[co] = v;
    }
}

__global__ void k_fin(const float* __restrict__ S, const float* __restrict__ S2,
                      float* __restrict__ mout, int COUT) {
    int c = threadIdx.x;
    if (c < COUT) {
        float m = S[c] * (1.0f / NZ);
        float var = S2[c] * (1.0f / NZ) - m * m;
        mout[c] = m;
        mout[64 + c] = rsqrtf(fmaxf(var, 0.f) + EPSV);
    }
}

__global__ void k_head(const float* __restrict__ Wb, const float* __restrict__ mp3,
                       float* __restrict__ Wf2, float* __restrict__ base,
                       float* __restrict__ corr) {
    __shared__ float sWW[512];
    int t = threadIdx.x;
    int ci = t >> 4, o = t & 15;
    float s = 0.f;
    for (int k = 0; k < 16; k++)
        s += Wb[WPO + ci * 16 + k] * Wb[WLO + k * 16 + o];
    float m = mp3[ci], rs = mp3[64 + ci];
    Wf2[t] = rs * s;
    sWW[t] = m * rs * s;
    __syncthreads();
    if (t < 16) {
        float v = Wb[BLO + t];
        for (int k = 0; k < 16; k++) v += Wb[BPO + k] * Wb[WLO + k * 16 + t];
        base[t] = v;
        float cr = 0.f;
        for (int c = 0; c < 32; c++) cr += sWW[c * 16 + t];
        corr[t] = cr;
    }
}

__global__ void k_out(const float* __restrict__ pool, const float* __restrict__ invc,
                      const int* __restrict__ cnt, const int* __restrict__ dflag,
                      const float* __restrict__ Wf2, const float* __restrict__ base,
                      const float* __restrict__ corr, void* __restrict__ out) {
    int flag = dflag[0];
    int t = blockIdx.x * 256 + threadIdx.x;
    int n = t >> 4, o = t & 15;
    float dot = 0.f;
    #pragma unroll 4
    for (int c = 0; c < 32; c++) dot += pool[(size_t)n * 32 + c] * Wf2[c * 16 + o];
    float corr_t = (cnt[n] > 0) ? corr[o] : 0.f;
    float v = base[o] - corr_t + invc[n] * dot;
    if (flag) ((bf16*)out)[t] = __float2bfloat16(v);
    else      ((float*)out)[t] = v;
}

// ==================== FAST PATH (bucketed, atomic-free) ====================

// multi-block exclusive scan of cnt[NE] -> off[NE+1]
__global__ __launch_bounds__(1024) void k_scan1(const int* __restrict__ cnt,
                                                int* __restrict__ blks) {
    __shared__ int s[1024];
    int idx = blockIdx.x * 1024 + threadIdx.x;
    s[threadIdx.x] = (idx < NE) ? cnt[idx] : 0;
    __syncthreads();
    #pragma unroll
    for (int d = 512; d > 0; d >>= 1) {
        if (threadIdx.x < d) s[threadIdx.x] += s[threadIdx.x + d];
        __syncthreads();
    }
    if (threadIdx.x == 0) blks[blockIdx.x] = s[0];
}

__global__ void k_scan2(const int* __restrict__ blks, int* __restrict__ blkoff,
                        int* __restrict__ off) {
    __shared__ int s[128];
    int t = threadIdx.x;
    int v = (t < NSB) ? blks[t] : 0;
    s[t] = v;
    __syncthreads();
    #pragma unroll
    for (int d = 1; d < 128; d <<= 1) {
        int a = (t >= d) ? s[t - d] : 0;
        __syncthreads();
        s[t] += a;
        __syncthreads();
    }
    if (t < NSB) blkoff[t] = s[t] - v;
    if (t == 127) off[NE] = s[127];   // == NZ
}

__global__ __launch_bounds__(1024) void k_scan3(const int* __restrict__ cnt,
                                                const int* __restrict__ blkoff,
                                                int* __restrict__ off) {
    __shared__ int s[1024];
    int idx = blockIdx.x * 1024 + threadIdx.x;
    int t = threadIdx.x;
    int v = (idx < NE) ? cnt[idx] : 0;
    s[t] = v;
    __syncthreads();
    #pragma unroll
    for (int d = 1; d < 1024; d <<= 1) {
        int a = (t >= d) ? s[t - d] : 0;
        __syncthreads();
        s[t] += a;
        __syncthreads();
    }
    if (idx < NE) off[idx] = blkoff[blockIdx.x] + s[t] - v;
}

__global__ void k_scatter(const int* __restrict__ row, const int* __restrict__ perm,
                          const int* __restrict__ off,
                          int* __restrict__ tmp, int* __restrict__ bucket,
                          int* __restrict__ dflag) {
    int e = blockIdx.x * 256 + threadIdx.x;        // grid exactly NZ/256
    int n = row[e];
    int rk = atomicAdd(&tmp[n], 1);
    bucket[off[n] + rk] = e;
    // verify the symmetrization structure perm[e] == e +- NZ/2 (reference construction).
    if (perm[e] != PARTNER(e)) dflag[1] = 1;       // benign race: any write sets
}

// S0: node-gather raw sums of values (16 ch); 4 lanes/node; unroll x2; arithmetic partner.
// Also produces the global tm sum (folded k_tm).
__global__ __launch_bounds__(256) void k_gsv(const void* __restrict__ xv,
                                             const int* __restrict__ dflag,
                                             const int* __restrict__ bucket,
                                             const int* __restrict__ off,
                                             const int* __restrict__ perm,
                                             float* __restrict__ rawR, float* __restrict__ rawC,
                                             float* __restrict__ tmsum) {
    __shared__ float red[16];
    if (threadIdx.x < 16) red[threadIdx.x] = 0.f;
    __syncthreads();
    int flag = dflag[0];
    int g = blockIdx.x * 64 + (threadIdx.x >> 2);
    int q = threadIdx.x & 3;
    float4 r4 = {0,0,0,0}, c4 = {0,0,0,0};
    int e0 = 0, e1 = 0;
    if (g < NE) { e0 = off[g]; e1 = off[g + 1]; }
    if (dflag[1] == 0) {
        int idx = e0;
        for (; idx + 1 < e1; idx += 2) {
            int i0 = bucket[idx], i1 = bucket[idx + 1];
            int p0 = PARTNER(i0), p1 = PARTNER(i1);
            float4 va0 = fin4(ld_x4(xv, flag, (size_t)i0 * 4 + q));
            float4 vb0 = fin4(ld_x4(xv, flag, (size_t)p0 * 4 + q));
            float4 va1 = fin4(ld_x4(xv, flag, (size_t)i1 * 4 + q));
            float4 vb1 = fin4(ld_x4(xv, flag, (size_t)p1 * 4 + q));
            ADD4(r4, va0); ADD4(c4, vb0);
            ADD4(r4, va1); ADD4(c4, vb1);
        }
        if (idx < e1) {
            int i = bucket[idx], p = PARTNER(i);
            float4 va = fin4(ld_x4(xv, flag, (size_t)i * 4 + q));
            float4 vb = fin4(ld_x4(xv, flag, (size_t)p * 4 + q));
            ADD4(r4, va); ADD4(c4, vb);
        }
    } else {
        for (int idx = e0; idx < e1; idx++) {
            int i = bucket[idx], p = perm[i];
            float4 va = fin4(ld_x4(xv, flag, (size_t)i * 4 + q));
            float4 vb = fin4(ld_x4(xv, flag, (size_t)p * 4 + q));
            ADD4(r4, va); ADD4(c4, vb);
        }
    }
    if (g < NE) {
        *(float4*)(rawR + (size_t)g * 64 + q * 4) = r4;
        *(float4*)(rawC + (size_t)g * 64 + q * 4) = c4;
    }
    atomicAdd(&red[q * 4 + 0], r4.x); atomicAdd(&red[q * 4 + 1], r4.y);
    atomicAdd(&red[q * 4 + 2], r4.z); atomicAdd(&red[q * 4 + 3], r4.w);
    __syncthreads();
    if (threadIdx.x < 16) unsafeAtomicAdd(&tmsum[threadIdx.x], red[threadIdx.x]);
}

// node kernel -> bf16 A/B tables; rm=(raw*invc - m*[cnt>0])*rs
template<int CIN, int COUT>
__global__ __launch_bounds__(256) void k_nodeb(const float* __restrict__ inR,
                                               const float* __restrict__ inC,
                                               const float* __restrict__ invc,
                                               const int* __restrict__ cnt,
                                               const float* __restrict__ mp,
                                               const float* __restrict__ W,
                                               bf16* __restrict__ outA, bf16* __restrict__ outB) {
    constexpr int QC = COUT / 4;
    constexpr int G  = 256 / QC;
    __shared__ __align__(16) float W2s[CIN*COUT], W3s[CIN*COUT], W4s[CIN*COUT], W5s[CIN*COUT];
    __shared__ __align__(16) float rmS[G*CIN], cmS[G*CIN];
    for (int i = threadIdx.x; i < CIN * COUT; i += 256) {
        W2s[i] = W[2 * CIN * COUT + i];
        W3s[i] = W[3 * CIN * COUT + i];
        W4s[i] = W[4 * CIN * COUT + i];
        W5s[i] = W[5 * CIN * COUT + i];
    }
    int n0 = blockIdx.x * G;
    for (int i = threadIdx.x; i < G * CIN; i += 256) {
        int g = i / CIN, ci = i % CIN;
        int n = n0 + g;
        float ic = invc[n];
        float mt = (cnt[n] > 0) ? mp[ci] : 0.f;
        float rs = mp[64 + ci];
        rmS[i] = (inR[(size_t)n * 64 + ci] * ic - mt) * rs;
        cmS[i] = (inC[(size_t)n * 64 + ci] * ic - mt) * rs;
    }
    __syncthreads();
    int g = threadIdx.x / QC, q = threadIdx.x % QC;
    int n = n0 + g;
    float4 a = {0,0,0,0}, b = {0,0,0,0};
    #pragma unroll 4
    for (int ci = 0; ci < CIN; ci++) {
        float rm = rmS[g * CIN + ci], cm = cmS[g * CIN + ci];
        float4 w2 = *(const float4*)(W2s + ci * COUT + q * 4);
        float4 w3 = *(const float4*)(W3s + ci * COUT + q * 4);
        float4 w4 = *(const float4*)(W4s + ci * COUT + q * 4);
        float4 w5 = *(const float4*)(W5s + ci * COUT + q * 4);
        FMA4S(a, rm, w2); FMA4S(a, cm, w4);
        FMA4S(b, rm, w3); FMA4S(b, cm, w5);
    }
    st_bf4(outA + (size_t)n * COUT + q * 4, a);
    st_bf4(outB + (size_t)n * COUT + q * 4, b);
}

// k_l1n: entry-parallel (quad/entry), writes h1 bf16, stats. (legacy fast path)
__global__ __launch_bounds__(256) void k_l1n(const void* __restrict__ xv,
                                             const int* __restrict__ dflag,
                                             const int* __restrict__ row, const int* __restrict__ col,
                                             const int* __restrict__ perm,
                                             const float* __restrict__ Wb,
                                             const float* __restrict__ c01,
                                             const bf16* __restrict__ A1b, const bf16* __restrict__ B1b,
                                             bf16* __restrict__ h1,
                                             float* __restrict__ Ssum, float* __restrict__ S2sum) {
    const int flag = dflag[0];
    __shared__ __align__(16) float W10s[512], W11s[512];
    __shared__ __align__(16) float c01s[32];
    __shared__ float red[64];
    for (int i = threadIdx.x; i < 512; i += 256) {
        W10s[i] = Wb[W1O + i];
        W11s[i] = Wb[W1O + 512 + i];
    }
    if (threadIdx.x < 32) c01s[threadIdx.x] = c01[threadIdx.x];
    if (threadIdx.x < 64) red[threadIdx.x] = 0.f;
    __syncthreads();
    const int e = blockIdx.x * 64 + (threadIdx.x >> 2);   // grid exactly NZ/64
    const int j = threadIdx.x & 3;
    const int o = j * 8;
    int r = row[e], c = col[e], p = perm[e];
    float xe[16], xp[16];
    #pragma unroll
    for (int i4 = 0; i4 < 4; i4++) {
        float4 va = fin4(ld_x4(xv, flag, (size_t)e * 4 + i4));
        float4 vb = fin4(ld_x4(xv, flag, (size_t)p * 4 + i4));
        xe[i4*4+0]=va.x; xe[i4*4+1]=va.y; xe[i4*4+2]=va.z; xe[i4*4+3]=va.w;
        xp[i4*4+0]=vb.x; xp[i4*4+1]=vb.y; xp[i4*4+2]=vb.z; xp[i4*4+3]=vb.w;
    }
    float4 alo = ld_bf4(A1b + (size_t)r * 32 + o);
    float4 ahi = ld_bf4(A1b + (size_t)r * 32 + o + 4);
    float4 blo = ld_bf4(B1b + (size_t)c * 32 + o);
    float4 bhi = ld_bf4(B1b + (size_t)c * 32 + o + 4);
    float ae[8];
    ae[0]=c01s[o+0]+alo.x+blo.x; ae[1]=c01s[o+1]+alo.y+blo.y;
    ae[2]=c01s[o+2]+alo.z+blo.z; ae[3]=c01s[o+3]+alo.w+blo.w;
    ae[4]=c01s[o+4]+ahi.x+bhi.x; ae[5]=c01s[o+5]+ahi.y+bhi.y;
    ae[6]=c01s[o+6]+ahi.z+bhi.z; ae[7]=c01s[o+7]+ahi.w+bhi.w;
    #pragma unroll
    for (int ci = 0; ci < 16; ci++) {
        const float* w0 = W10s + ci * 32 + o;
        const float* w1 = W11s + ci * 32 + o;
        float a = xe[ci], b = xp[ci];
        #pragma unroll
        for (int u = 0; u < 8; u++) ae[u] += a * w0[u] + b * w1[u];
    }
    float4 hlo, hhi;
    hlo.x=fmaxf(ae[0],0.f); hlo.y=fmaxf(ae[1],0.f); hlo.z=fmaxf(ae[2],0.f); hlo.w=fmaxf(ae[3],0.f);
    hhi.x=fmaxf(ae[4],0.f); hhi.y=fmaxf(ae[5],0.f); hhi.z=fmaxf(ae[6],0.f); hhi.w=fmaxf(ae[7],0.f);
    st_bf4(h1 + (size_t)e * 32 + o, hlo);
    st_bf4(h1 + (size_t)e * 32 + o + 4, hhi);
    #pragma unroll
    for (int u = 0; u < 8; u++) {
        float h = fmaxf(ae[u], 0.f);
        atomicAdd(&red[o + u], h);
        atomicAdd(&red[32 + o + u], h * h);
    }
    __syncthreads();
    if (threadIdx.x < 32) {
        unsafeAtomicAdd(&Ssum[threadIdx.x], red[threadIdx.x]);
        unsafeAtomicAdd(&S2sum[threadIdx.x], red[32 + threadIdx.x]);
    }
}

// S1: node-gather raw sums of h1 (32 ch); 4 lanes/node; unroll x4; arithmetic partner.
template<bool STATS>
__global__ __launch_bounds__(256) void k_gsh1(const bf16* __restrict__ h1,
                                              const int* __restrict__ bucket,
                                              const int* __restrict__ off,
                                              const int* __restrict__ perm,
                                              const int* __restrict__ dflag,
                                              float* __restrict__ rawR, float* __restrict__ rawC,
                                              float* __restrict__ Ssum, float* __restrict__ S2sum) {
    __shared__ float red[64];
    if (STATS) {
        if (threadIdx.x < 64) red[threadIdx.x] = 0.f;
        __syncthreads();
    }
    int g = blockIdx.x * 64 + (threadIdx.x >> 2);   // grid ceil(NE/64)
    int q = threadIdx.x & 3;
    float4 ra = {0,0,0,0}, rb = {0,0,0,0}, ca = {0,0,0,0}, cb = {0,0,0,0};
    float4 sa = {0,0,0,0}, sb = {0,0,0,0};
    int e0 = 0, e1 = 0;
    if (g < NE) { e0 = off[g]; e1 = off[g + 1]; }
    const bf16* hk = h1 + q * 8;
    if (dflag[1] == 0) {
        int idx = e0;
        for (; idx + 3 < e1; idx += 4) {
            int i0 = bucket[idx],     i1 = bucket[idx + 1];
            int i2 = bucket[idx + 2], i3 = bucket[idx + 3];
            uint4 u0 = *(const uint4*)(hk + (size_t)i0 * 32);
            uint4 v0 = *(const uint4*)(hk + (size_t)PARTNER(i0) * 32);
            uint4 u1 = *(const uint4*)(hk + (size_t)i1 * 32);
            uint4 v1 = *(const uint4*)(hk + (size_t)PARTNER(i1) * 32);
            uint4 u2 = *(const uint4*)(hk + (size_t)i2 * 32);
            uint4 v2 = *(const uint4*)(hk + (size_t)PARTNER(i2) * 32);
            uint4 u3 = *(const uint4*)(hk + (size_t)i3 * 32);
            uint4 v3 = *(const uint4*)(hk + (size_t)PARTNER(i3) * 32);
            float4 L, H;
            cv_bf8(u0, L, H); ADD4(ra, L); ADD4(rb, H); if (STATS) { SQ4(sa, L); SQ4(sb, H); }
            cv_bf8(u1, L, H); ADD4(ra, L); ADD4(rb, H); if (STATS) { SQ4(sa, L); SQ4(sb, H); }
            cv_bf8(u2, L, H); ADD4(ra, L); ADD4(rb, H); if (STATS) { SQ4(sa, L); SQ4(sb, H); }
            cv_bf8(u3, L, H); ADD4(ra, L); ADD4(rb, H); if (STATS) { SQ4(sa, L); SQ4(sb, H); }
            cv_bf8(v0, L, H); ADD4(ca, L); ADD4(cb, H);
            cv_bf8(v1, L, H); ADD4(ca, L); ADD4(cb, H);
            cv_bf8(v2, L, H); ADD4(ca, L); ADD4(cb, H);
            cv_bf8(v3, L, H); ADD4(ca, L); ADD4(cb, H);
        }
        for (; idx < e1; idx++) {
            int i = bucket[idx], p = PARTNER(i);
            float4 aL, aH, bL, bH;
            ld_bf8v(hk + (size_t)i * 32, aL, aH);
            ld_bf8v(hk + (size_t)p * 32, bL, bH);
            ADD4(ra, aL); ADD4(rb, aH); ADD4(ca, bL); ADD4(cb, bH);
            if (STATS) { SQ4(sa, aL); SQ4(sb, aH); }
        }
    } else {
        for (int idx = e0; idx < e1; idx++) {
            int i = bucket[idx], p = perm[i];
            float4 aL, aH, bL, bH;
            ld_bf8v(hk + (size_t)i * 32, aL, aH);
            ld_bf8v(hk + (size_t)p * 32, bL, bH);
            ADD4(ra, aL); ADD4(rb, aH); ADD4(ca, bL); ADD4(cb, bH);
            if (STATS) { SQ4(sa, aL); SQ4(sb, aH); }
        }
    }
    if (g < NE) {
        *(float4*)(rawR + (size_t)g * 64 + q * 8) = ra;
        *(float4*)(rawR + (size_t)g * 64 + q * 8 + 4) = rb;
        *(float4*)(rawC + (size_t)g * 64 + q * 8) = ca;
        *(float4*)(rawC + (size_t)g * 64 + q * 8 + 4) = cb;
    }
    if (STATS) {
        int o = q * 8;
        atomicAdd(&red[o+0], ra.x); atomicAdd(&red[o+1], ra.y);
        atomicAdd(&red[o+2], ra.z); atomicAdd(&red[o+3], ra.w);
        atomicAdd(&red[o+4], rb.x); atomicAdd(&red[o+5], rb.y);
        atomicAdd(&red[o+6], rb.z); atomicAdd(&red[o+7], rb.w);
        atomicAdd(&red[32+o+0], sa.x); atomicAdd(&red[32+o+1], sa.y);
        atomicAdd(&red[32+o+2], sa.z); atomicAdd(&red[32+o+3], sa.w);
        atomicAdd(&red[32+o+4], sb.x); atomicAdd(&red[32+o+5], sb.y);
        atomicAdd(&red[32+o+6], sb.z); atomicAdd(&red[32+o+7], sb.w);
        __syncthreads();
        if (threadIdx.x < 32) {
            unsafeAtomicAdd(&Ssum[threadIdx.x], red[threadIdx.x]);
            unsafeAtomicAdd(&S2sum[threadIdx.x], red[32 + threadIdx.x]);
        }
    }
}

// ---------- MFMA path: weight folding ----------
template<int KH, int COUT>
__global__ void k_fold(const float* __restrict__ W, const float* __restrict__ mp,
                       const float* __restrict__ c0, bf16* __restrict__ Wfs,
                       float* __restrict__ c0f) {
    int t = blockIdx.x * 256 + threadIdx.x;     // grid = 16 blocks -> 4096 threads
    constexpr int NT = COUT / 16;
    int f = t >> 9, r = t & 511;
    int lane = r >> 3, j = r & 7;
    int kc = f / NT, nt = f % NT;
    int kl = ((lane >> 4) << 3) + j;
    int kg = kc * 32 + kl;
    int n  = nt * 16 + (lane & 15);
    float w = 0.f;
    if (kg < 2 * KH) {
        int k  = (kg < KH) ? kg : kg - KH;
        const float* Ws = W + ((kg < KH) ? 0 : KH * COUT);
        w = Ws[k * COUT + n] * mp[64 + k];
    }
    bf16 hi = __float2bfloat16(w);
    Wfs[t] = hi;
    Wfs[4096 + t] = __float2bfloat16(w - __bfloat162float(hi));
    if (t < COUT) {
        float acc = c0[t];
        for (int k2 = 0; k2 < KH; k2++)
            acc += (-mp[k2] * mp[64 + k2]) * (W[k2 * COUT + t] + W[KH * COUT + k2 * COUT + t]);
        c0f[t] = acc;
    }
}

// ---------- MFMA layer-1 edge pass ----------
__global__ __launch_bounds__(256) void k_l1e(const void* __restrict__ xv,
                                             const int* __restrict__ dflag,
                                             const int* __restrict__ row,
                                             const int* __restrict__ col,
                                             const int* __restrict__ perm,
                                             const bf16* __restrict__ Wfs,
                                             const float* __restrict__ c0f,
                                             const bf16* __restrict__ A1b,
                                             const bf16* __restrict__ B1b,
                                             bf16* __restrict__ h1) {
    __shared__ __align__(16) float tr[4][16 * 36];   // per-wave 16x32 transpose, pad 36
    __shared__ __align__(16) float c0s[32];
    if (threadIdx.x < 32) c0s[threadIdx.x] = c0f[threadIdx.x];
    const int flag = dflag[0];
    const int vio  = dflag[1];
    const int wv  = threadIdx.x >> 6;
    const int l   = threadIdx.x & 63;
    const int lr  = l & 15;
    const int lk  = l >> 4;          // k-group: k = lk*8 + j
    const int tb  = lk * 4;
    float* T = tr[wv];
    short8v bh[2], bl[2];
    bh[0] = *(const short8v*)(Wfs + 0 * 512 + l * 8);
    bh[1] = *(const short8v*)(Wfs + 1 * 512 + l * 8);
    bl[0] = *(const short8v*)(Wfs + 4096 + 0 * 512 + l * 8);
    bl[1] = *(const short8v*)(Wfs + 4096 + 1 * 512 + l * 8);
    const int eE = l >> 2, q = l & 3;
    const int kq = lk & 1;           // which 8-ch half of the 16 input channels
    __syncthreads();
    for (int bt = blockIdx.x; bt < NZ / 64; bt += gridDim.x) {
        const int te = bt * 64 + wv * 16;
        const int eA = te + lr;
        const int src = (lk < 2) ? eA : (vio ? perm[eA] : PARTNER(eA));
        float xr[8];
        float4 v0 = fin4(ld_x4(xv, flag, (size_t)src * 4 + kq * 2));
        float4 v1 = fin4(ld_x4(xv, flag, (size_t)src * 4 + kq * 2 + 1));
        xr[0]=v0.x; xr[1]=v0.y; xr[2]=v0.z; xr[3]=v0.w;
        xr[4]=v1.x; xr[5]=v1.y; xr[6]=v1.z; xr[7]=v1.w;
        short8v ah, al;
        split8(xr, ah, al);
        f32x4 ac0 = {0.f, 0.f, 0.f, 0.f};
        f32x4 ac1 = ac0;
        ac0 = MFMA_B16(ah, bh[0], ac0); ac1 = MFMA_B16(ah, bh[1], ac1);
        ac0 = MFMA_B16(ah, bl[0], ac0); ac1 = MFMA_B16(ah, bl[1], ac1);
        ac0 = MFMA_B16(al, bh[0], ac0); ac1 = MFMA_B16(al, bh[1], ac1);
        #pragma unroll
        for (int r = 0; r < 4; r++) {
            float* Tw = T + (tb + r) * 36 + lr;
            Tw[0] = ac0[r]; Tw[16] = ac1[r];
        }
        __syncthreads();
        {
            const int e  = te + eE;
            const int rr = row[e], cc = col[e];
            const float* Tp = T + eE * 36 + q * 8;
            const bf16* ap = A1b + (size_t)rr * 32 + q * 8;
            const bf16* bp = B1b + (size_t)cc * 32 + q * 8;
            const float* cp = c0s + q * 8;
            float4 hv0 = relu4s(*(const float4*)(Tp + 0), ld_bf4(ap + 0), ld_bf4(bp + 0), cp + 0);
            float4 hv1 = relu4s(*(const float4*)(Tp + 4), ld_bf4(ap + 4), ld_bf4(bp + 4), cp + 4);
            st_bf8(h1 + (size_t)e * 32 + q * 8, hv0, hv1);
        }
        __syncthreads();
    }
}

// ---------- MFMA layer-2 edge pass ----------
__global__ __launch_bounds__(256) void k_l2e(const bf16* __restrict__ h1,
                                             const int* __restrict__ row,
                                             const int* __restrict__ col,
                                             const int* __restrict__ perm,
                                             const int* __restrict__ dflag,
                                             const bf16* __restrict__ Wfs,
                                             const float* __restrict__ c0f,
                                             const bf16* __restrict__ A2b,
                                             const bf16* __restrict__ B2b,
                                             bf16* __restrict__ h2) {
    __shared__ __align__(16) float tr[4][16 * 68];   // per-wave 16x64 transpose, pad 68
    __shared__ __align__(16) float c0s[64];
    if (threadIdx.x < 64) c0s[threadIdx.x] = c0f[threadIdx.x];
    const int vio = dflag[1];
    const int wv  = threadIdx.x >> 6;
    const int l   = threadIdx.x & 63;
    const int lr  = l & 15;
    const int lk8 = (l >> 4) * 8;
    const int tb  = (l >> 4) * 4;
    float* T = tr[wv];
    short8v bh[8], bl[8];
    #pragma unroll
    for (int f = 0; f < 8; f++) {
        bh[f] = *(const short8v*)(Wfs + f * 512 + l * 8);
        bl[f] = *(const short8v*)(Wfs + 4096 + f * 512 + l * 8);
    }
    const int eE = l >> 2, q = l & 3;
    __syncthreads();
    for (int bt = blockIdx.x; bt < NZ / 64; bt += gridDim.x) {
        const int te = bt * 64 + wv * 16;
        const int eA = te + lr;
        const int pA = vio ? perm[eA] : PARTNER(eA);
        short8v a0 = *(const short8v*)(h1 + (size_t)eA * 32 + lk8);
        short8v a1 = *(const short8v*)(h1 + (size_t)pA * 32 + lk8);
        f32x4 ac0 = {0.f, 0.f, 0.f, 0.f};
        f32x4 ac1 = ac0, ac2 = ac0, ac3 = ac0;
        ac0 = MFMA_B16(a0, bh[0], ac0);  ac1 = MFMA_B16(a0, bh[1], ac1);
        ac2 = MFMA_B16(a0, bh[2], ac2);  ac3 = MFMA_B16(a0, bh[3], ac3);
        ac0 = MFMA_B16(a1, bh[4], ac0);  ac1 = MFMA_B16(a1, bh[5], ac1);
        ac2 = MFMA_B16(a1, bh[6], ac2);  ac3 = MFMA_B16(a1, bh[7], ac3);
        ac0 = MFMA_B16(a0, bl[0], ac0);  ac1 = MFMA_B16(a0, bl[1], ac1);
        ac2 = MFMA_B16(a0, bl[2], ac2);  ac3 = MFMA_B16(a0, bl[3], ac3);
        ac0 = MFMA_B16(a1, bl[4], ac0);  ac1 = MFMA_B16(a1, bl[5], ac1);
        ac2 = MFMA_B16(a1, bl[6], ac2);  ac3 = MFMA_B16(a1, bl[7], ac3);
        #pragma unroll
        for (int r = 0; r < 4; r++) {   // C: row=(l>>4)*4+r, col=lr (+16*nt)
            float* Tw = T + (tb + r) * 68 + lr;
            Tw[0] = ac0[r]; Tw[16] = ac1[r]; Tw[32] = ac2[r]; Tw[48] = ac3[r];
        }
        __syncthreads();
        {
            const int e  = te + eE;
            const int rr = row[e], cc = col[e];
            const float* Tp = T + eE * 68 + q * 16;
            const bf16* ap = A2b + (size_t)rr * 64 + q * 16;
            const bf16* bp = B2b + (size_t)cc * 64 + q * 16;
            const float* cp = c0s + q * 16;
            float4 hv0 = relu4s(*(const float4*)(Tp + 0),  ld_bf4(ap + 0),  ld_bf4(bp + 0),  cp + 0);
            float4 hv1 = relu4s(*(const float4*)(Tp + 4),  ld_bf4(ap + 4),  ld_bf4(bp + 4),  cp + 4);
            float4 hv2 = relu4s(*(const float4*)(Tp + 8),  ld_bf4(ap + 8),  ld_bf4(bp + 8),  cp + 8);
            float4 hv3 = relu4s(*(const float4*)(Tp + 12), ld_bf4(ap + 12), ld_bf4(bp + 12), cp + 12);
            st_bf8(h2 + (size_t)e * 64 + q * 16, hv0, hv1);
            st_bf8(h2 + (size_t)e * 64 + q * 16 + 8, hv2, hv3);
        }
        __syncthreads();
    }
}

// node-gather raw sums of h2 (64 ch) + layer-2 stats; 8 lanes/node; unroll x4; arithmetic partner.
__global__ __launch_bounds__(256) void k_gs64(const bf16* __restrict__ h2,
                                              const int* __restrict__ bucket,
                                              const int* __restrict__ off,
                                              const int* __restrict__ perm,
                                              const int* __restrict__ dflag,
                                              float* __restrict__ rawR, float* __restrict__ rawC,
                                              float* __restrict__ Ssum, float* __restrict__ S2sum) {
    __shared__ float red[128];
    if (threadIdx.x < 128) red[threadIdx.x] = 0.f;
    __syncthreads();
    int g = blockIdx.x * 32 + (threadIdx.x >> 3);   // grid exactly NE/32
    int k = threadIdx.x & 7;
    float4 ra = {0,0,0,0}, rb = {0,0,0,0}, ca = {0,0,0,0}, cb = {0,0,0,0};
    float4 sa = {0,0,0,0}, sb = {0,0,0,0};
    int e0 = off[g], e1 = off[g + 1];
    const bf16* hk = h2 + k * 8;
    if (dflag[1] == 0) {
        int idx = e0;
        for (; idx + 3 < e1; idx += 4) {
            int i0 = bucket[idx],     i1 = bucket[idx + 1];
            int i2 = bucket[idx + 2], i3 = bucket[idx + 3];
            uint4 u0 = *(const uint4*)(hk + (size_t)i0 * 64);
            uint4 v0 = *(const uint4*)(hk + (size_t)PARTNER(i0) * 64);
            uint4 u1 = *(const uint4*)(hk + (size_t)i1 * 64);
            uint4 v1 = *(const uint4*)(hk + (size_t)PARTNER(i1) * 64);
            uint4 u2 = *(const uint4*)(hk + (size_t)i2 * 64);
            uint4 v2 = *(const uint4*)(hk + (size_t)PARTNER(i2) * 64);
            uint4 u3 = *(const uint4*)(hk + (size_t)i3 * 64);
            uint4 v3 = *(const uint4*)(hk + (size_t)PARTNER(i3) * 64);
            float4 L, H;
            cv_bf8(u0, L, H); ADD4(ra, L); ADD4(rb, H); SQ4(sa, L); SQ4(sb, H);
            cv_bf8(u1, L, H); ADD4(ra, L); ADD4(rb, H); SQ4(sa, L); SQ4(sb, H);
            cv_bf8(u2, L, H); ADD4(ra, L); ADD4(rb, H); SQ4(sa, L); SQ4(sb, H);
            cv_bf8(u3, L, H); ADD4(ra, L); ADD4(rb, H); SQ4(sa, L); SQ4(sb, H);
            cv_bf8(v0, L, H); ADD4(ca, L); ADD4(cb, H);
            cv_bf8(v1, L, H); ADD4(ca, L); ADD4(cb, H);
            cv_bf8(v2, L, H); ADD4(ca, L); ADD4(cb, H);
            cv_bf8(v3, L, H); ADD4(ca, L); ADD4(cb, H);
        }
        for (; idx < e1; idx++) {
            int i = bucket[idx], p = PARTNER(i);
            float4 aL, aH, bL, bH;
            ld_bf8v(hk + (size_t)i * 64, aL, aH);
            ld_bf8v(hk + (size_t)p * 64, bL, bH);
            ADD4(ra, aL); ADD4(rb, aH); ADD4(ca, bL); ADD4(cb, bH);
            SQ4(sa, aL); SQ4(sb, aH);
        }
    } else {
        for (int idx = e0; idx < e1; idx++) {
            int i = bucket[idx], p = perm[i];
            float4 aL, aH, bL, bH;
            ld_bf8v(hk + (size_t)i * 64, aL, aH);
            ld_bf8v(hk + (size_t)p * 64, bL, bH);
            ADD4(ra, aL); ADD4(rb, aH); ADD4(ca, bL); ADD4(cb, bH);
            SQ4(sa, aL); SQ4(sb, aH);
        }
    }
    *(float4*)(rawR + (size_t)g * 64 + k * 8) = ra;
    *(float4*)(rawR + (size_t)g * 64 + k * 8 + 4) = rb;
    *(float4*)(rawC + (size_t)g * 64 + k * 8) = ca;
    *(float4*)(rawC + (size_t)g * 64 + k * 8 + 4) = cb;
    {
        int o = k * 8;
        atomicAdd(&red[o+0], ra.x); atomicAdd(&red[o+1], ra.y);
        atomicAdd(&red[o+2], ra.z); atomicAdd(&red[o+3], ra.w);
        atomicAdd(&red[o+4], rb.x); atomicAdd(&red[o+5], rb.y);
        atomicAdd(&red[o+6], rb.z); atomicAdd(&red[o+7], rb.w);
        atomicAdd(&red[64+o+0], sa.x); atomicAdd(&red[64+o+1], sa.y);
        atomicAdd(&red[64+o+2], sa.z); atomicAdd(&red[64+o+3], sa.w);
        atomicAdd(&red[64+o+4], sb.x); atomicAdd(&red[64+o+5], sb.y);
        atomicAdd(&red[64+o+6], sb.z); atomicAdd(&red[64+o+7], sb.w);
    }
    __syncthreads();
    if (threadIdx.x < 64) {
        unsafeAtomicAdd(&Ssum[threadIdx.x], red[threadIdx.x]);
        unsafeAtomicAdd(&S2sum[threadIdx.x], red[64 + threadIdx.x]);
    }
}

// ---------- MFMA layer-3 edge pass (fused pooling + layer-3 stats; no h3) ----------
__global__ __launch_bounds__(256) void k_l3e(const bf16* __restrict__ h2,
                                             const int* __restrict__ row,
                                             const int* __restrict__ col,
                                             const int* __restrict__ perm,
                                             const int* __restrict__ dflag,
                                             const bf16* __restrict__ Wfs,
                                             const float* __restrict__ c0f,
                                             const bf16* __restrict__ A3b,
                                             const bf16* __restrict__ B3b,
                                             float* __restrict__ pool,
                                             float* __restrict__ Ssum, float* __restrict__ S2sum) {
    __shared__ __align__(16) float tr[4][16 * 36];   // per-wave 16x32 transpose, pad 36
    __shared__ __align__(16) float c0s[32];
    __shared__ float red[64];
    if (threadIdx.x < 32) c0s[threadIdx.x] = c0f[threadIdx.x];
    if (threadIdx.x < 64) red[threadIdx.x] = 0.f;
    const int vio = dflag[1];
    const int wv  = threadIdx.x >> 6;
    const int l   = threadIdx.x & 63;
    const int lr  = l & 15;
    const int lk8 = (l >> 4) * 8;
    const int tb  = (l >> 4) * 4;
    float* T = tr[wv];
    short8v bh[8], bl[8];
    #pragma unroll
    for (int f = 0; f < 8; f++) {
        bh[f] = *(const short8v*)(Wfs + f * 512 + l * 8);
        bl[f] = *(const short8v*)(Wfs + 4096 + f * 512 + l * 8);
    }
    const int eE = l >> 2, q = l & 3;
    float4 s1a = {0,0,0,0}, s1b = {0,0,0,0}, s2a = {0,0,0,0}, s2b = {0,0,0,0};
    __syncthreads();
    for (int bt = blockIdx.x; bt < NZ / 64; bt += gridDim.x) {
        const int te = bt * 64 + wv * 16;
        const int eA = te + lr;
        const int pA = vio ? perm[eA] : PARTNER(eA);
        const bf16* he = h2 + (size_t)eA * 64;
        const bf16* hp = h2 + (size_t)pA * 64;
        short8v a0 = *(const short8v*)(he + lk8);
        short8v a1 = *(const short8v*)(he + 32 + lk8);
        short8v a2 = *(const short8v*)(hp + lk8);
        short8v a3 = *(const short8v*)(hp + 32 + lk8);
        f32x4 ac0 = {0.f, 0.f, 0.f, 0.f};
        f32x4 ac1 = ac0;
        ac0 = MFMA_B16(a0, bh[0], ac0); ac1 = MFMA_B16(a0, bh[1], ac1);
        ac0 = MFMA_B16(a1, bh[2], ac0); ac1 = MFMA_B16(a1, bh[3], ac1);
        ac0 = MFMA_B16(a2, bh[4], ac0); ac1 = MFMA_B16(a2, bh[5], ac1);
        ac0 = MFMA_B16(a3, bh[6], ac0); ac1 = MFMA_B16(a3, bh[7], ac1);
        ac0 = MFMA_B16(a0, bl[0], ac0); ac1 = MFMA_B16(a0, bl[1], ac1);
        ac0 = MFMA_B16(a1, bl[2], ac0); ac1 = MFMA_B16(a1, bl[3], ac1);
        ac0 = MFMA_B16(a2, bl[4], ac0); ac1 = MFMA_B16(a2, bl[5], ac1);
        ac0 = MFMA_B16(a3, bl[6], ac0); ac1 = MFMA_B16(a3, bl[7], ac1);
        #pragma unroll
        for (int r = 0; r < 4; r++) {
            float* Tw = T + (tb + r) * 36 + lr;
            Tw[0] = ac0[r]; Tw[16] = ac1[r];
        }
        __syncthreads();
        {
            const int e  = te + eE;
            const int rr = row[e], cc = col[e];
            const float* Tp = T + eE * 36 + q * 8;
            const bf16* ap = A3b + (size_t)rr * 32 + q * 8;
            const bf16* bp = B3b + (size_t)cc * 32 + q * 8;
            const float* cp = c0s + q * 8;
            float4 hv0 = relu4s(*(const float4*)(Tp + 0), ld_bf4(ap + 0), ld_bf4(bp + 0), cp + 0);
            float4 hv1 = relu4s(*(const float4*)(Tp + 4), ld_bf4(ap + 4), ld_bf4(bp + 4), cp + 4);
            float* pp = pool + (size_t)rr * 32 + q * 8;
            unsafeAtomicAdd(pp + 0, hv0.x); unsafeAtomicAdd(pp + 1, hv0.y);
            unsafeAtomicAdd(pp + 2, hv0.z); unsafeAtomicAdd(pp + 3, hv0.w);
            unsafeAtomicAdd(pp + 4, hv1.x); unsafeAtomicAdd(pp + 5, hv1.y);
            unsafeAtomicAdd(pp + 6, hv1.z); unsafeAtomicAdd(pp + 7, hv1.w);
            ADD4(s1a, hv0); ADD4(s1b, hv1);
            SQ4(s2a, hv0); SQ4(s2b, hv1);
        }
        __syncthreads();
    }
    {
        int o = q * 8;
        atomicAdd(&red[o+0], s1a.x); atomicAdd(&red[o+1], s1a.y);
        atomicAdd(&red[o+2], s1a.z); atomicAdd(&red[o+3], s1a.w);
        atomicAdd(&red[o+4], s1b.x); atomicAdd(&red[o+5], s1b.y);
        atomicAdd(&red[o+6], s1b.z); atomicAdd(&red[o+7], s1b.w);
        atomicAdd(&red[32+o+0], s2a.x); atomicAdd(&red[32+o+1], s2a.y);
        atomicAdd(&red[32+o+2], s2a.z); atomicAdd(&red[32+o+3], s2a.w);
        atomicAdd(&red[32+o+4], s2b.x); atomicAdd(&red[32+o+5], s2b.y);
        atomicAdd(&red[32+o+6], s2b.z); atomicAdd(&red[32+o+7], s2b.w);
    }
    __syncthreads();
    if (threadIdx.x < 32) {
        unsafeAtomicAdd(&Ssum[threadIdx.x], red[threadIdx.x]);
        unsafeAtomicAdd(&S2sum[threadIdx.x], red[32 + threadIdx.x]);
    }
}

// ==================== legacy fast-path compute kernels (fallback if ws too small) ====================

__global__ __launch_bounds__(256) void k_gsh2(const bf16* __restrict__ h1,
                                              const int* __restrict__ bucket,
                                              const int* __restrict__ off,
                                              const int* __restrict__ perm,
                                              const int* __restrict__ col,
                                              const float* __restrict__ Wb,
                                              const float* __restrict__ mp1,
                                              const float* __restrict__ c02,
                                              const bf16* __restrict__ A2b, const bf16* __restrict__ B2b,
                                              float* __restrict__ rawR, float* __restrict__ rawC,
                                              float* __restrict__ Ssum, float* __restrict__ S2sum) {
    __shared__ __align__(16) float W20s[2048], W21s[2048];
    __shared__ __align__(16) float nm1s[32], rs1s[32], c02s[64];
    __shared__ float red[128];
    for (int i = threadIdx.x; i < 2048; i += 256) {
        W20s[i] = Wb[W2O + i];
        W21s[i] = Wb[W2O + 2048 + i];
    }
    if (threadIdx.x < 32) {
        float m = mp1[threadIdx.x], rr = mp1[64 + threadIdx.x];
        nm1s[threadIdx.x] = -m * rr; rs1s[threadIdx.x] = rr;
    }
    if (threadIdx.x < 64) c02s[threadIdx.x] = c02[threadIdx.x];
    if (threadIdx.x < 128) red[threadIdx.x] = 0.f;
    __syncthreads();
    const int g    = blockIdx.x * 16 + (threadIdx.x >> 4);   // grid exactly NE/16
    const int lane = threadIdx.x & 15;
    const int gb   = (threadIdx.x & 63) & ~15;
    const int myo  = lane * 4;
    float4 a2n = ld_bf4(A2b + (size_t)g * 64 + myo);
    float4 b2n = ld_bf4(B2b + (size_t)g * 64 + myo);
    float4 cc  = *(const float4*)(c02s + myo);
    float rA = rs1s[lane*2], rB = rs1s[lane*2+1];
    float nA = nm1s[lane*2], nB = nm1s[lane*2+1];
    float4 racc = {0,0,0,0}, cacc = {0,0,0,0}, st1 = {0,0,0,0}, st2 = {0,0,0,0};
    int e0 = off[g], e1 = off[g + 1];
    for (int idx = e0; idx < e1; idx++) {
        int i = bucket[idx], p = perm[i], c = col[i];
        float2 hi2 = ld_bf2(h1 + (size_t)i * 32 + lane * 2);
        float2 hp2 = ld_bf2(h1 + (size_t)p * 32 + lane * 2);
        float xi0 = hi2.x * rA + nA, xi1 = hi2.y * rB + nB;
        float xp0 = hp2.x * rA + nA, xp1 = hp2.y * rB + nB;
        float4 a2c = ld_bf4(A2b + (size_t)c * 64 + myo);
        float4 b2c = ld_bf4(B2b + (size_t)c * 64 + myo);
        float4 ai, ap;
        ai.x = cc.x + a2n.x + b2c.x; ai.y = cc.y + a2n.y + b2c.y;
        ai.z = cc.z + a2n.z + b2c.z; ai.w = cc.w + a2n.w + b2c.w;
        ap.x = cc.x + a2c.x + b2n.x; ap.y = cc.y + a2c.y + b2n.y;
        ap.z = cc.z + a2c.z + b2n.z; ap.w = cc.w + a2c.w + b2n.w;
        #pragma unroll
        for (int s = 0; s < 16; s++) {
            float va0 = __shfl(xi0, gb + s, 64), va1 = __shfl(xi1, gb + s, 64);
            float vb0 = __shfl(xp0, gb + s, 64), vb1 = __shfl(xp1, gb + s, 64);
            float4 W0a = *(const float4*)(W20s + (2*s)   * 64 + myo);
            float4 W0b = *(const float4*)(W20s + (2*s+1) * 64 + myo);
            float4 W1a = *(const float4*)(W21s + (2*s)   * 64 + myo);
            float4 W1b = *(const float4*)(W21s + (2*s+1) * 64 + myo);
            FMA4S(ai, va0, W0a); FMA4S(ai, va1, W0b);
            FMA4S(ai, vb0, W1a); FMA4S(ai, vb1, W1b);
            FMA4S(ap, vb0, W0a); FMA4S(ap, vb1, W0b);
            FMA4S(ap, va0, W1a); FMA4S(ap, va1, W1b);
        }
        float4 h2i, h2p;
        h2i.x=fmaxf(ai.x,0.f); h2i.y=fmaxf(ai.y,0.f); h2i.z=fmaxf(ai.z,0.f); h2i.w=fmaxf(ai.w,0.f);
        h2p.x=fmaxf(ap.x,0.f); h2p.y=fmaxf(ap.y,0.f); h2p.z=fmaxf(ap.z,0.f); h2p.w=fmaxf(ap.w,0.f);
        ADD4(racc, h2i); ADD4(cacc, h2p); ADD4(st1, h2i);
        st2.x += h2i.x*h2i.x; st2.y += h2i.y*h2i.y; st2.z += h2i.z*h2i.z; st2.w += h2i.w*h2i.w;
    }
    *(float4*)(rawR + (size_t)g * 64 + myo) = racc;
    *(float4*)(rawC + (size_t)g * 64 + myo) = cacc;
    atomicAdd(&red[myo+0], st1.x); atomicAdd(&red[myo+1], st1.y);
    atomicAdd(&red[myo+2], st1.z); atomicAdd(&red[myo+3], st1.w);
    atomicAdd(&red[64+myo+0], st2.x); atomicAdd(&red[64+myo+1], st2.y);
    atomicAdd(&red[64+myo+2], st2.z); atomicAdd(&red[64+myo+3], st2.w);
    __syncthreads();
    if (threadIdx.x < 64) {
        unsafeAtomicAdd(&Ssum[threadIdx.x], red[threadIdx.x]);
        unsafeAtomicAdd(&S2sum[threadIdx.x], red[64 + threadIdx.x]);
    }
}

__global__ __launch_bounds__(256) void k_l3n(const bf16* __restrict__ h1,
                                             const int* __restrict__ bucket,
                                             const int* __restrict__ off,
                                             const int* __restrict__ perm,
                                             const int* __restrict__ col,
                                             const float* __restrict__ Wb,
                                             const float* __restrict__ mp1,
                                             const float* __restrict__ c02,
                                             const bf16* __restrict__ A2b, const bf16* __restrict__ B2b,
                                             const float* __restrict__ mp2,
                                             const float* __restrict__ c03,
                                             const bf16* __restrict__ A3b, const bf16* __restrict__ B3b,
                                             float* __restrict__ pool,
                                             float* __restrict__ Ssum, float* __restrict__ S2sum) {
    __shared__ __align__(16) float W20s[2048], W21s[2048], W30s[2048], W31s[2048];
    __shared__ __align__(16) float nm1s[32], rs1s[32], nm2s[64], rs2s[64], c02s[64], c03s[32];
    __shared__ float red[64];
    for (int i = threadIdx.x; i < 2048; i += 256) {
        W20s[i] = Wb[W2O + i];
        W21s[i] = Wb[W2O + 2048 + i];
        W30s[i] = Wb[W3O + i];
        W31s[i] = Wb[W3O + 2048 + i];
    }
    if (threadIdx.x < 32) {
        float m = mp1[threadIdx.x], rr = mp1[64 + threadIdx.x];
        nm1s[threadIdx.x] = -m * rr; rs1s[threadIdx.x] = rr;
        c03s[threadIdx.x] = c03[threadIdx.x];
    }
    if (threadIdx.x < 64) {
        float m = mp2[threadIdx.x], rr = mp2[64 + threadIdx.x];
        nm2s[threadIdx.x] = -m * rr; rs2s[threadIdx.x] = rr;
        c02s[threadIdx.x] = c02[threadIdx.x];
        red[threadIdx.x] = 0.f;
    }
    __syncthreads();
    const int g    = blockIdx.x * 16 + (threadIdx.x >> 4);   // grid exactly NE/16
    const int lane = threadIdx.x & 15;
    const int gb   = (threadIdx.x & 63) & ~15;
    const int myo  = lane * 4;
    const int myo3 = lane * 2;
    float4 a2n = ld_bf4(A2b + (size_t)g * 64 + myo);
    float4 b2n = ld_bf4(B2b + (size_t)g * 64 + myo);
    float4 cc  = *(const float4*)(c02s + myo);
    float2 a3n = ld_bf2(A3b + (size_t)g * 32 + myo3);
    float rA = rs1s[lane*2], rB = rs1s[lane*2+1];
    float nA = nm1s[lane*2], nB = nm1s[lane*2+1];
    float rs20 = rs2s[myo+0], rs21 = rs2s[myo+1], rs22 = rs2s[myo+2], rs23 = rs2s[myo+3];
    float nm20 = nm2s[myo+0], nm21 = nm2s[myo+1], nm22 = nm2s[myo+2], nm23 = nm2s[myo+3];
    float2 pacc = {0,0}, st1 = {0,0}, st2 = {0,0};
    int e0 = off[g], e1 = off[g + 1];
    for (int idx = e0; idx < e1; idx++) {
        int i = bucket[idx], p = perm[i], c = col[i];
        float2 hi2 = ld_bf2(h1 + (size_t)i * 32 + lane * 2);
        float2 hp2 = ld_bf2(h1 + (size_t)p * 32 + lane * 2);
        float xi0 = hi2.x * rA + nA, xi1 = hi2.y * rB + nB;
        float xp0 = hp2.x * rA + nA, xp1 = hp2.y * rB + nB;
        float4 a2c = ld_bf4(A2b + (size_t)c * 64 + myo);
        float4 b2c = ld_bf4(B2b + (size_t)c * 64 + myo);
        float4 ai, ap;
        ai.x = cc.x + a2n.x + b2c.x; ai.y = cc.y + a2n.y + b2c.y;
        ai.z = cc.z + a2n.z + b2c.z; ai.w = cc.w + a2n.w + b2c.w;
        ap.x = cc.x + a2c.x + b2n.x; ap.y = cc.y + a2c.y + b2n.y;
        ap.z = cc.z + a2c.z + b2n.z; ap.w = cc.w + a2c.w + b2n.w;
        #pragma unroll
        for (int s = 0; s < 16; s++) {
            float va0 = __shfl(xi0, gb + s, 64), va1 = __shfl(xi1, gb + s, 64);
            float vb0 = __shfl(xp0, gb + s, 64), vb1 = __shfl(xp1, gb + s, 64);
            float4 W0a = *(const float4*)(W20s + (2*s)   * 64 + myo);
            float4 W0b = *(const float4*)(W20s + (2*s+1) * 64 + myo);
            float4 W1a = *(const float4*)(W21s + (2*s)   * 64 + myo);
            float4 W1b = *(const float4*)(W21s + (2*s+1) * 64 + myo);
            FMA4S(ai, va0, W0a); FMA4S(ai, va1, W0b);
            FMA4S(ai, vb0, W1a); FMA4S(ai, vb1, W1b);
            FMA4S(ap, vb0, W0a); FMA4S(ap, vb1, W0b);
            FMA4S(ap, va0, W1a); FMA4S(ap, va1, W1b);
        }
        float he0 = fmaxf(ai.x,0.f)*rs20+nm20, he1 = fmaxf(ai.y,0.f)*rs21+nm21;
        float he2 = fmaxf(ai.z,0.f)*rs22+nm22, he3 = fmaxf(ai.w,0.f)*rs23+nm23;
        float hq0 = fmaxf(ap.x,0.f)*rs20+nm20, hq1 = fmaxf(ap.y,0.f)*rs21+nm21;
        float hq2 = fmaxf(ap.z,0.f)*rs22+nm22, hq3 = fmaxf(ap.w,0.f)*rs23+nm23;
        float2 b3c = ld_bf2(B3b + (size_t)c * 32 + myo3);
        float a30 = a3n.x + b3c.x + c03s[myo3];
        float a31 = a3n.y + b3c.y + c03s[myo3 + 1];
        #pragma unroll
        for (int s = 0; s < 16; s++) {
            float e0v = __shfl(he0, gb+s, 64), e1v = __shfl(he1, gb+s, 64);
            float e2v = __shfl(he2, gb+s, 64), e3v = __shfl(he3, gb+s, 64);
            float q0v = __shfl(hq0, gb+s, 64), q1v = __shfl(hq1, gb+s, 64);
            float q2v = __shfl(hq2, gb+s, 64), q3v = __shfl(hq3, gb+s, 64);
            const float* w30 = W30s + (4*s) * 32 + myo3;
            const float* w31 = W31s + (4*s) * 32 + myo3;
            a30 += e0v*w30[0]    + q0v*w31[0];
            a31 += e0v*w30[1]    + q0v*w31[1];
            a30 += e1v*w30[32]   + q1v*w31[32];
            a31 += e1v*w30[33]   + q1v*w31[33];
            a30 += e2v*w30[64]   + q2v*w31[64];
            a31 += e2v*w30[65]   + q2v*w31[65];
            a30 += e3v*w30[96]   + q3v*w31[96];
            a31 += e3v*w30[97]   + q3v*w31[97];
        }
        float h30 = fmaxf(a30, 0.f), h31 = fmaxf(a31, 0.f);
        pacc.x += h30; pacc.y += h31;
        st1.x += h30; st1.y += h31;
        st2.x += h30 * h30; st2.y += h31 * h31;
    }
    *(float2*)(pool + (size_t)g * 32 + myo3) = pacc;
    atomicAdd(&red[myo3], st1.x); atomicAdd(&red[myo3 + 1], st1.y);
    atomicAdd(&red[32 + myo3], st2.x); atomicAdd(&red[32 + myo3 + 1], st2.y);
    __syncthreads();
    if (threadIdx.x < 32) {
        unsafeAtomicAdd(&Ssum[threadIdx.x], red[threadIdx.x]);
        unsafeAtomicAdd(&S2sum[threadIdx.x], red[32 + threadIdx.x]);
    }
}

// ==================== FALLBACK PATH (R4, atomic seg sums) ====================

__global__ __launch_bounds__(256) void k_seg1(const void* __restrict__ xv,
                                              const int* __restrict__ dflag,
                                              const int* __restrict__ row,
                                              const int* __restrict__ col,
                                              float* __restrict__ rsum, float* __restrict__ csum) {
    int flag = dflag[0];
    int t = blockIdx.x * 256 + threadIdx.x;
    int e = t >> 2, q = t & 3;
    float4 xvv = fin4(ld_x4(xv, flag, (size_t)t));
    float* rp = rsum + (size_t)row[e] * 64 + q * 4;
    float* cp = csum + (size_t)col[e] * 64 + q * 4;
    unsafeAtomicAdd(rp + 0, xvv.x); unsafeAtomicAdd(rp + 1, xvv.y);
    unsafeAtomicAdd(rp + 2, xvv.z); unsafeAtomicAdd(rp + 3, xvv.w);
    unsafeAtomicAdd(cp + 0, xvv.x); unsafeAtomicAdd(cp + 1, xvv.y);
    unsafeAtomicAdd(cp + 2, xvv.z); unsafeAtomicAdd(cp + 3, xvv.w);
}

template<int CIN, int COUT, int OST>
__global__ __launch_bounds__(256) void k_node(const float* __restrict__ inR,
                                              const float* __restrict__ inC,
                                              const float* __restrict__ invc,
                                              const float* __restrict__ mp,
                                              const float* __restrict__ W,
                                              float* __restrict__ outA, float* __restrict__ outB) {
    constexpr int QC = COUT / 4;
    constexpr int G  = 256 / QC;
    __shared__ __align__(16) float W2s[CIN*COUT], W3s[CIN*COUT], W4s[CIN*COUT], W5s[CIN*COUT];
    __shared__ __align__(16) float rmS[G*CIN], cmS[G*CIN];
    for (int i = threadIdx.x; i < CIN * COUT; i += 256) {
        W2s[i] = W[2 * CIN * COUT + i];
        W3s[i] = W[3 * CIN * COUT + i];
        W4s[i] = W[4 * CIN * COUT + i];
        W5s[i] = W[5 * CIN * COUT + i];
    }
    int n0 = blockIdx.x * G;
    for (int i = threadIdx.x; i < G * CIN; i += 256) {
        int g = i / CIN, ci = i % CIN;
        int n = n0 + g;
        float ic = invc[n];
        float m = mp[ci], rs = mp[64 + ci];
        rmS[i] = (inR[(size_t)n * 64 + ci] * ic - m) * rs;
        cmS[i] = (inC[(size_t)n * 64 + ci] * ic - m) * rs;
    }
    __syncthreads();
    int g = threadIdx.x / QC, q = threadIdx.x % QC;
    int n = n0 + g;
    float4 a = {0,0,0,0}, b = {0,0,0,0};
    #pragma unroll 4
    for (int ci = 0; ci < CIN; ci++) {
        float rm = rmS[g * CIN + ci], cm = cmS[g * CIN + ci];
        float4 w2 = *(const float4*)(W2s + ci * COUT + q * 4);
        float4 w3 = *(const float4*)(W3s + ci * COUT + q * 4);
        float4 w4 = *(const float4*)(W4s + ci * COUT + q * 4);
        float4 w5 = *(const float4*)(W5s + ci * COUT + q * 4);
        FMA4S(a, rm, w2); FMA4S(a, cm, w4);
        FMA4S(b, rm, w3); FMA4S(b, cm, w5);
    }
    *(float4*)(outA + (size_t)n * OST + q * 4) = a;
    *(float4*)(outB + (size_t)n * OST + q * 4) = b;
}

__global__ __launch_bounds__(256) void k_l1(const void* __restrict__ xv,
                                            const int* __restrict__ dflag,
                                            const int* __restrict__ row, const int* __restrict__ col,
                                            const int* __restrict__ perm,
                                            const float* __restrict__ Wb,
                                            const float* __restrict__ c01,
                                            const float* __restrict__ A1, const float* __restrict__ B1,
                                            float* __restrict__ segR, float* __restrict__ segC,
                                            float* __restrict__ Ssum, float* __restrict__ S2sum) {
    const int flag = dflag[0];
    __shared__ __align__(16) float W10s[512], W11s[512];
    __shared__ __align__(16) float c01s[32];
    __shared__ float red[64];
    for (int i = threadIdx.x; i < 512; i += 256) {
        W10s[i] = Wb[W1O + i];
        W11s[i] = Wb[W1O + 512 + i];
    }
    if (threadIdx.x < 32) c01s[threadIdx.x] = c01[threadIdx.x];
    if (threadIdx.x < 64) red[threadIdx.x] = 0.f;
    __syncthreads();
    const int j = threadIdx.x & 3;
    const int o = j * 8;
    float s1[8] = {0,0,0,0,0,0,0,0}, s2[8] = {0,0,0,0,0,0,0,0};
    for (int e = blockIdx.x * 64 + (threadIdx.x >> 2); e < NZ; e += gridDim.x * 64) {
        int r = row[e], c = col[e], p = perm[e];
        float xe[16], xp[16];
        #pragma unroll
        for (int i4 = 0; i4 < 4; i4++) {
            float4 va = fin4(ld_x4(xv, flag, (size_t)e * 4 + i4));
            float4 vb = fin4(ld_x4(xv, flag, (size_t)p * 4 + i4));
            xe[i4*4+0]=va.x; xe[i4*4+1]=va.y; xe[i4*4+2]=va.z; xe[i4*4+3]=va.w;
            xp[i4*4+0]=vb.x; xp[i4*4+1]=vb.y; xp[i4*4+2]=vb.z; xp[i4*4+3]=vb.w;
        }
        float ae[8];
        #pragma unroll
        for (int u2 = 0; u2 < 2; u2++) {
            float4 a1 = *(const float4*)(A1 + (size_t)r * 32 + o + u2 * 4);
            float4 b1 = *(const float4*)(B1 + (size_t)c * 32 + o + u2 * 4);
            float4 ccv = *(const float4*)(c01s + o + u2 * 4);
            ae[u2*4+0]=ccv.x+a1.x+b1.x; ae[u2*4+1]=ccv.y+a1.y+b1.y;
            ae[u2*4+2]=ccv.z+a1.z+b1.z; ae[u2*4+3]=ccv.w+a1.w+b1.w;
        }
        #pragma unroll
        for (int ci = 0; ci < 16; ci++) {
            const float* w0 = W10s + ci * 32 + o;
            const float* w1 = W11s + ci * 32 + o;
            float a = xe[ci], b = xp[ci];
            #pragma unroll
            for (int u = 0; u < 8; u++) ae[u] += a * w0[u] + b * w1[u];
        }
        float* rp = segR + (size_t)r * 64 + o;
        float* cp = segC + (size_t)c * 64 + o;
        #pragma unroll
        for (int u = 0; u < 8; u++) {
            float h = fmaxf(ae[u], 0.f);
            s1[u] += h; s2[u] += h * h;
            unsafeAtomicAdd(rp + u, h);
            unsafeAtomicAdd(cp + u, h);
        }
    }
    #pragma unroll
    for (int u = 0; u < 8; u++) {
        atomicAdd(&red[o + u], s1[u]);
        atomicAdd(&red[32 + o + u], s2[u]);
    }
    __syncthreads();
    if (threadIdx.x < 32) {
        unsafeAtomicAdd(&Ssum[threadIdx.x], red[threadIdx.x]);
        unsafeAtomicAdd(&S2sum[threadIdx.x], red[32 + threadIdx.x]);
    }
}

template<bool FINAL>
__global__ __launch_bounds__(256) void k_pair(const void* __restrict__ xv,
                                              const int* __restrict__ dflag,
                                              const int* __restrict__ row, const int* __restrict__ col,
                                              const int* __restrict__ perm,
                                              const float* __restrict__ Wb,
                                              const float* __restrict__ c01,
                                              const float* __restrict__ A1, const float* __restrict__ B1,
                                              const float* __restrict__ mp1,
                                              const float* __restrict__ c02,
                                              const float* __restrict__ A2, const float* __restrict__ B2,
                                              const float* __restrict__ mp2,
                                              const float* __restrict__ c03,
                                              const float* __restrict__ A3, const float* __restrict__ B3,
                                              float* __restrict__ segR, float* __restrict__ segC,
                                              float* __restrict__ Ssum, float* __restrict__ S2sum) {
    const int flag = dflag[0];
    constexpr int NCH = FINAL ? 32 : 64;
    __shared__ __align__(16) float W10s[512], W11s[512];
    __shared__ __align__(16) float W20s[2048], W21s[2048];
    __shared__ __align__(16) float W30s[2048], W31s[2048];
    __shared__ __align__(16) float c01s[32], nm1s[32], rs1s[32];
    __shared__ __align__(16) float c02s[64], nm2s[64], rs2s[64], c03s[32];
    __shared__ float red[2 * NCH];
    for (int i = threadIdx.x; i < 512; i += 256) {
        W10s[i] = Wb[W1O + i];
        W11s[i] = Wb[W1O + 512 + i];
    }
    for (int i = threadIdx.x; i < 2048; i += 256) {
        W20s[i] = Wb[W2O + i];
        W21s[i] = Wb[W2O + 2048 + i];
        if (FINAL) {
            W30s[i] = Wb[W3O + i];
            W31s[i] = Wb[W3O + 2048 + i];
        }
    }
    if (threadIdx.x < 32) {
        c01s[threadIdx.x] = c01[threadIdx.x];
        float m = mp1[threadIdx.x], rr = mp1[64 + threadIdx.x];
        nm1s[threadIdx.x] = -m * rr; rs1s[threadIdx.x] = rr;
        if (FINAL) c03s[threadIdx.x] = c03[threadIdx.x];
    }
    if (threadIdx.x < 64) {
        c02s[threadIdx.x] = c02[threadIdx.x];
        if (FINAL) {
            float m = mp2[threadIdx.x], rr = mp2[64 + threadIdx.x];
            nm2s[threadIdx.x] = -m * rr; rs2s[threadIdx.x] = rr;
        }
    }
    if (threadIdx.x < 2 * NCH) red[threadIdx.x] = 0.f;
    __syncthreads();
    const int j  = threadIdx.x & 3;
    const int qb = (threadIdx.x & 63) & ~3;
    constexpr int LCH = FINAL ? 8 : 16;
    float s1[LCH], s2[LCH];
    #pragma unroll
    for (int k = 0; k < LCH; k++) { s1[k] = 0.f; s2[k] = 0.f; }
    for (int e = blockIdx.x * 64 + (threadIdx.x >> 2); e < NZ; e += gridDim.x * 64) {
        int r = row[e], c = col[e], p = perm[e];
        float xe[16], xp[16];
        #pragma unroll
        for (int i4 = 0; i4 < 4; i4++) {
            float4 va = fin4(ld_x4(xv, flag, (size_t)e * 4 + i4));
            float4 vb = fin4(ld_x4(xv, flag, (size_t)p * 4 + i4));
            xe[i4*4+0]=va.x; xe[i4*4+1]=va.y; xe[i4*4+2]=va.z; xe[i4*4+3]=va.w;
            xp[i4*4+0]=vb.x; xp[i4*4+1]=vb.y; xp[i4*4+2]=vb.z; xp[i4*4+3]=vb.w;
        }
        const int o1 = j * 8;
        float ae[8], ap[8];
        #pragma unroll
        for (int u2 = 0; u2 < 2; u2++) {
            float4 a1r = *(const float4*)(A1 + (size_t)r * 32 + o1 + u2 * 4);
            float4 b1c = *(const float4*)(B1 + (size_t)c * 32 + o1 + u2 * 4);
            float4 a1c = *(const float4*)(A1 + (size_t)c * 32 + o1 + u2 * 4);
            float4 b1r = *(const float4*)(B1 + (size_t)r * 32 + o1 + u2 * 4);
            float4 ccv = *(const float4*)(c01s + o1 + u2 * 4);
            ae[u2*4+0]=ccv.x+a1r.x+b1c.x; ae[u2*4+1]=ccv.y+a1r.y+b1c.y;
            ae[u2*4+2]=ccv.z+a1r.z+b1c.z; ae[u2*4+3]=ccv.w+a1r.w+b1c.w;
            ap[u2*4+0]=ccv.x+a1c.x+b1r.x; ap[u2*4+1]=ccv.y+a1c.y+b1r.y;
            ap[u2*4+2]=ccv.z+a1c.z+b1r.z; ap[u2*4+3]=ccv.w+a1c.w+b1r.w;
        }
        #pragma unroll
        for (int ci = 0; ci < 16; ci++) {
            const float* w0 = W10s + ci * 32 + o1;
            const float* w1 = W11s + ci * 32 + o1;
            float a = xe[ci], b = xp[ci];
            #pragma unroll
            for (int u = 0; u < 8; u++) {
                ae[u] += a * w0[u] + b * w1[u];
                ap[u] += b * w0[u] + a * w1[u];
            }
        }
        #pragma unroll
        for (int u = 0; u < 8; u++) {
            ae[u] = fmaxf(ae[u], 0.f) * rs1s[o1 + u] + nm1s[o1 + u];
            ap[u] = fmaxf(ap[u], 0.f) * rs1s[o1 + u] + nm1s[o1 + u];
        }
        const int o2 = j * 16;
        float be[16], bp[16];
        #pragma unroll
        for (int t4 = 0; t4 < 4; t4++) {
            float4 a2r = *(const float4*)(A2 + (size_t)r * 64 + o2 + t4 * 4);
            float4 b2c = *(const float4*)(B2 + (size_t)c * 64 + o2 + t4 * 4);
            float4 ccv = *(const float4*)(c02s + o2 + t4 * 4);
            be[t4*4+0]=ccv.x+a2r.x+b2c.x; be[t4*4+1]=ccv.y+a2r.y+b2c.y;
            be[t4*4+2]=ccv.z+a2r.z+b2c.z; be[t4*4+3]=ccv.w+a2r.w+b2c.w;
            if (FINAL) {
                float4 a2c = *(const float4*)(A2 + (size_t)c * 64 + o2 + t4 * 4);
                float4 b2r = *(const float4*)(B2 + (size_t)r * 64 + o2 + t4 * 4);
                bp[t4*4+0]=ccv.x+a2c.x+b2r.x; bp[t4*4+1]=ccv.y+a2c.y+b2r.y;
                bp[t4*4+2]=ccv.z+a2c.z+b2r.z; bp[t4*4+3]=ccv.w+a2c.w+b2r.w;
            }
        }
        #pragma unroll
        for (int l = 0; l < 4; l++) {
            #pragma unroll
            for (int u = 0; u < 8; u++) {
                float a = __shfl(ae[u], qb + l, 64);
                float b = __shfl(ap[u], qb + l, 64);
                const float* w0 = W20s + (l * 8 + u) * 64 + o2;
                const float* w1 = W21s + (l * 8 + u) * 64 + o2;
                #pragma unroll
                for (int t = 0; t < 16; t++) {
                    be[t] += a * w0[t] + b * w1[t];
                    if (FINAL) bp[t] += b * w0[t] + a * w1[t];
                }
            }
        }
        if (!FINAL) {
            float* rp = segR + (size_t)r * 64 + o2;
            float* cp = segC + (size_t)c * 64 + o2;
            #pragma unroll
            for (int t = 0; t < 16; t++) {
                float h = fmaxf(be[t], 0.f);
                s1[t] += h; s2[t] += h * h;
                unsafeAtomicAdd(rp + t, h);
                unsafeAtomicAdd(cp + t, h);
            }
        } else {
            #pragma unroll
            for (int t = 0; t < 16; t++) {
                be[t] = fmaxf(be[t], 0.f) * rs2s[o2 + t] + nm2s[o2 + t];
                bp[t] = fmaxf(bp[t], 0.f) * rs2s[o2 + t] + nm2s[o2 + t];
            }
            float a3[8];
            #pragma unroll
            for (int u2 = 0; u2 < 2; u2++) {
                float4 a3r = *(const float4*)(A3 + (size_t)r * 32 + o1 + u2 * 4);
                float4 b3c = *(const float4*)(B3 + (size_t)c * 32 + o1 + u2 * 4);
                float4 ccv = *(const float4*)(c03s + o1 + u2 * 4);
                a3[u2*4+0]=ccv.x+a3r.x+b3c.x; a3[u2*4+1]=ccv.y+a3r.y+b3c.y;
                a3[u2*4+2]=ccv.z+a3r.z+b3c.z; a3[u2*4+3]=ccv.w+a3r.w+b3c.w;
            }
            #pragma unroll
            for (int l = 0; l < 4; l++) {
                #pragma unroll
                for (int t = 0; t < 16; t++) {
                    float a = __shfl(be[t], qb + l, 64);
                    float b = __shfl(bp[t], qb + l, 64);
                    const float* w0 = W30s + (l * 16 + t) * 32 + o1;
                    const float* w1 = W31s + (l * 16 + t) * 32 + o1;
                    #pragma unroll
                    for (int u = 0; u < 8; u++)
                        a3[u] += a * w0[u] + b * w1[u];
                }
            }
            float* pp = segR + (size_t)r * 32 + o1;
            #pragma unroll
            for (int u = 0; u < 8; u++) {
                float h = fmaxf(a3[u], 0.f);
                s1[u] += h; s2[u] += h * h;
                unsafeAtomicAdd(pp + u, h);
            }
        }
    }
    {
        const int ob = FINAL ? (j * 8) : (j * 16);
        #pragma unroll
        for (int k = 0; k < LCH; k++) {
            atomicAdd(&red[ob + k], s1[k]);
            atomicAdd(&red[NCH + ob + k], s2[k]);
        }
    }
    __syncthreads();
    if (threadIdx.x < NCH) {
        unsafeAtomicAdd(&Ssum[threadIdx.x], red[threadIdx.x]);
        unsafeAtomicAdd(&S2sum[threadIdx.x], red[NCH + threadIdx.x]);
    }
}

// ---------- host ----------
extern "C" void kernel_launch(void* const* d_in, const int* in_sizes, int n_in,
                              void* d_out, int out_size, void* d_ws, size_t ws_size,
                              hipStream_t stream) {
    const void* values = d_in[0];
    const int* row  = (const int*)d_in[1];
    const int* col  = (const int*)d_in[2];
    const int* perm = (const int*)d_in[3];

    char* p = (char*)d_ws;
    auto carve = [&](size_t bytes) { char* r = p; p += (bytes + 255) & ~(size_t)255; return r; };

    // ---------- fast2 (MFMA) carve, ~406 MB ----------
    bf16* h1     = (bf16*)carve((size_t)NZ * 32 * 2);     // 102.4 MB
    bf16* h2     = (bf16*)carve((size_t)NZ * 64 * 2);     // 204.8 MB
    int*  bucket = (int*)carve((size_t)NZ * 4);           // 6.4 MB
    int*  off    = (int*)carve((size_t)(NE + 1) * 4);
    int*  tmp    = (int*)carve((size_t)NE * 4);
    int*  sblk   = (int*)carve(256 * 4);                  // scan block sums + offsets
    float* rawR  = (float*)carve((size_t)NE * 64 * 4);    // 25.6 MB (pool aliases)
    float* rawC  = (float*)carve((size_t)NE * 64 * 4);    // 25.6 MB
    bf16* A2b    = (bf16*)carve((size_t)NE * 64 * 2);     // 12.8 MB
    bf16* B2b    = (bf16*)carve((size_t)NE * 64 * 2);
    bf16* Qa     = (bf16*)carve((size_t)NE * 32 * 2);     // A1 then A3
    bf16* Qb     = (bf16*)carve((size_t)NE * 32 * 2);     // B1 then B3
    bf16* W1fs   = (bf16*)carve(8192 * 2);                // hi+lo folded W1 frags
    bf16* W2fs   = (bf16*)carve(8192 * 2);                // hi+lo folded W2 frags
    bf16* W3fs   = (bf16*)carve(8192 * 2);                // hi+lo folded W3 frags
    int*   cnt   = (int*)carve((size_t)NE * 4);
    float* invc  = (float*)carve((size_t)NE * 4);
    float* Wbuf  = (float*)carve((size_t)WTOT * 4);
    float* misc  = (float*)carve(2048 * 4);
    int*   dflag = (int*)carve(64 * 4);
    size_t need_fast2 = (size_t)(p - (char*)d_ws);
    // misc (floats): mp0@0, mp1@128, mp2@256, mp3@384 (m@+0, rs@+64)
    //   S@512/576/640, S2@768/832/896, tmsum@960, c0@1024/1088/1152,
    //   Wf2@1280, base@1792, corr@1808, c02f@1856, c03f@1920, c01f@1984

    if (ws_size >= need_fast2) {
        float* pool = rawR;     // rawR dead after k_nodeb<64,32>
        hipMemsetAsync(misc, 0, 2048 * 4, stream);
        hipMemsetAsync(cnt, 0, (size_t)NE * 4, stream);
        hipMemsetAsync(tmp, 0, (size_t)NE * 4, stream);
        k_detect<<<1, 64, 0, stream>>>((const unsigned*)values, dflag);
        k_convW<<<(WTOT + 255) / 256, 256, 0, stream>>>(d_in[4], d_in[5], d_in[6], d_in[7],
                                                        d_in[8], d_in[9], d_in[10], d_in[11],
                                                        d_in[12], d_in[13], dflag, Wbuf);
        k_prep<<<1, 64, 0, stream>>>(misc);
        k_count<<<NZ / 256, 256, 0, stream>>>(row, cnt);
        k_invcnt<<<(NE + 255) / 256, 256, 0, stream>>>(cnt, invc);
        k_scan1<<<NSB, 1024, 0, stream>>>(cnt, sblk);
        k_scan2<<<1, 128, 0, stream>>>(sblk, sblk + 128, off);
        k_scan3<<<NSB, 1024, 0, stream>>>(cnt, sblk + 128, off);
        k_scatter<<<NZ / 256, 256, 0, stream>>>(row, perm, off, tmp, bucket, dflag);

        // layer 1 (MFMA edge pass; tm folded into gsv)
        k_gsv<<<(NE + 63) / 64, 256, 0, stream>>>(values, dflag, bucket, off, perm,
                                                  rawR, rawC, misc + 960);
        k_nodeb<16, 32><<<NE / 32, 256, 0, stream>>>(rawR, rawC, invc, cnt, misc + 0,
                                                     Wbuf + W1O, Qa, Qb);
        k_const<<<1, 64, 0, stream>>>(Wbuf + W1O, Wbuf + B1O, misc + 960, 1, misc + 1024, 16, 32);
        k_fold<16, 32><<<16, 256, 0, stream>>>(Wbuf + W1O, misc + 0, misc + 1024,
                                               W1fs, misc + 1984);
        k_l1e<<<2500, 256, 0, stream>>>(values, dflag, row, col, perm, W1fs, misc + 1984,
                                        Qa, Qb, h1);
        k_gsh1<true><<<(NE + 63) / 64, 256, 0, stream>>>(h1, bucket, off, perm, dflag,
                                                         rawR, rawC, misc + 512, misc + 768);
        k_fin<<<1, 64, 0, stream>>>(misc + 512, misc + 768, misc + 128, 32);

        // layer 2 (MFMA, materialized h2)
        k_nodeb<32, 64><<<NE / 16, 256, 0, stream>>>(rawR, rawC, invc, cnt, misc + 128,
                                                     Wbuf + W2O, A2b, B2b);
        k_const<<<1, 64, 0, stream>>>(Wbuf + W2O, Wbuf + B2O, misc + 960, 0, misc + 1088, 32, 64);
        k_fold<32, 64><<<16, 256, 0, stream>>>(Wbuf + W2O, misc + 128, misc + 1088,
                                               W2fs, misc + 1856);
        k_l2e<<<2500, 256, 0, stream>>>(h1, row, col, perm, dflag, W2fs, misc + 1856,
                                        A2b, B2b, h2);
        k_gs64<<<NE / 32, 256, 0, stream>>>(h2, bucket, off, perm, dflag, rawR, rawC,
                                            misc + 576, misc + 832);
        k_fin<<<1, 64, 0, stream>>>(misc + 576, misc + 832, misc + 256, 64);

        // layer 3 (MFMA, fused pool + stats)
        k_nodeb<64, 32><<<NE / 32, 256, 0, stream>>>(rawR, rawC, invc, cnt, misc + 256,
                                                     Wbuf + W3O, Qa, Qb);   // Qa/Qb = A3/B3
        k_const<<<1, 64, 0, stream>>>(Wbuf + W3O, Wbuf + B3O, misc + 960, 0, misc + 1152, 64, 32);
        k_fold<64, 32><<<16, 256, 0, stream>>>(Wbuf + W3O, misc + 256, misc + 1152,
                                               W3fs, misc + 1920);
        hipMemsetAsync(pool, 0, (size_t)NE * 32 * 4, stream);
        k_l3e<<<2500, 256, 0, stream>>>(h2, row, col, perm, dflag, W3fs, misc + 1920,
                                        Qa, Qb, pool, misc + 640, misc + 896);
        k_fin<<<1, 64, 0, stream>>>(misc + 640, misc + 896, misc + 384, 32);

        k_head<<<1, 512, 0, stream>>>(Wbuf, misc + 384, misc + 1280, misc + 1792, misc + 1808);
        k_out<<<NE * 16 / 256, 256, 0, stream>>>(pool, invc, cnt, dflag,
                                                 misc + 1280, misc + 1792, misc + 1808, d_out);
        return;
    }

    // ---------- legacy fast carve (~200 MB) ----------
    p = (char*)d_ws;
    h1     = (bf16*)carve((size_t)NZ * 32 * 2);
    bucket = (int*)carve((size_t)NZ * 4);
    off    = (int*)carve((size_t)(NE + 1) * 4);
    tmp    = (int*)carve((size_t)NE * 4);
    sblk   = (int*)carve(256 * 4);
    rawR   = (float*)carve((size_t)NE * 64 * 4);
    rawC   = (float*)carve((size_t)NE * 64 * 4);
    A2b    = (bf16*)carve((size_t)NE * 64 * 2);
    B2b    = (bf16*)carve((size_t)NE * 64 * 2);
    Qa     = (bf16*)carve((size_t)NE * 32 * 2);
    Qb     = (bf16*)carve((size_t)NE * 32 * 2);
    cnt    = (int*)carve((size_t)NE * 4);
    invc   = (float*)carve((size_t)NE * 4);
    Wbuf   = (float*)carve((size_t)WTOT * 4);
    misc   = (float*)carve(2048 * 4);
    dflag  = (int*)carve(64 * 4);
    size_t need_fast = (size_t)(p - (char*)d_ws);

    if (ws_size >= need_fast) {
        float* pool = rawR;
        hipMemsetAsync(misc, 0, 2048 * 4, stream);
        hipMemsetAsync(cnt, 0, (size_t)NE * 4, stream);
        hipMemsetAsync(tmp, 0, (size_t)NE * 4, stream);
        k_detect<<<1, 64, 0, stream>>>((const unsigned*)values, dflag);
        k_convW<<<(WTOT + 255) / 256, 256, 0, stream>>>(d_in[4], d_in[5], d_in[6], d_in[7],
                                                        d_in[8], d_in[9], d_in[10], d_in[11],
                                                        d_in[12], d_in[13], dflag, Wbuf);
        k_prep<<<1, 64, 0, stream>>>(misc);
        k_count<<<NZ / 256, 256, 0, stream>>>(row, cnt);
        k_invcnt<<<(NE + 255) / 256, 256, 0, stream>>>(cnt, invc);
        k_scan1<<<NSB, 1024, 0, stream>>>(cnt, sblk);
        k_scan2<<<1, 128, 0, stream>>>(sblk, sblk + 128, off);
        k_scan3<<<NSB, 1024, 0, stream>>>(cnt, sblk + 128, off);
        k_scatter<<<NZ / 256, 256, 0, stream>>>(row, perm, off, tmp, bucket, dflag);

        k_gsv<<<(NE + 63) / 64, 256, 0, stream>>>(values, dflag, bucket, off, perm,
                                                  rawR, rawC, misc + 960);
        k_nodeb<16, 32><<<NE / 32, 256, 0, stream>>>(rawR, rawC, invc, cnt, misc + 0,
                                                     Wbuf + W1O, Qa, Qb);
        k_const<<<1, 64, 0, stream>>>(Wbuf + W1O, Wbuf + B1O, misc + 960, 1, misc + 1024, 16, 32);
        k_l1n<<<NZ / 64, 256, 0, stream>>>(values, dflag, row, col, perm, Wbuf, misc + 1024,
                                           Qa, Qb, h1, misc + 512, misc + 768);
        k_fin<<<1, 64, 0, stream>>>(misc + 512, misc + 768, misc + 128, 32);

        k_gsh1<false><<<(NE + 63) / 64, 256, 0, stream>>>(h1, bucket, off, perm, dflag,
                                                          rawR, rawC, nullptr, nullptr);
        k_nodeb<32, 64><<<NE / 16, 256, 0, stream>>>(rawR, rawC, invc, cnt, misc + 128,
                                                     Wbuf + W2O, A2b, B2b);
        k_const<<<1, 64, 0, stream>>>(Wbuf + W2O, Wbuf + B2O, misc + 960, 0, misc + 1088, 32, 64);
        k_gsh2<<<NE / 16, 256, 0, stream>>>(h1, bucket, off, perm, col, Wbuf, misc + 128,
                                            misc + 1088, A2b, B2b, rawR, rawC,
                                            misc + 576, misc + 832);
        k_fin<<<1, 64, 0, stream>>>(misc + 576, misc + 832, misc + 256, 64);

        k_nodeb<64, 32><<<NE / 32, 256, 0, stream>>>(rawR, rawC, invc, cnt, misc + 256,
                                                     Wbuf + W3O, Qa, Qb);
        k_const<<<1, 64, 0, stream>>>(Wbuf + W3O, Wbuf + B3O, misc + 960, 0, misc + 1152, 64, 32);
        k_l3n<<<NE / 16, 256, 0, stream>>>(h1, bucket, off, perm, col, Wbuf, misc + 128,
                                           misc + 1088, A2b, B2b, misc + 256,
                                           misc + 1152, Qa, Qb, pool,
                                           misc + 640, misc + 896);
        k_fin<<<1, 64, 0, stream>>>(misc + 640, misc + 896, misc + 384, 32);

        k_head<<<1, 512, 0, stream>>>(Wbuf, misc + 384, misc + 1280, misc + 1792, misc + 1808);
        k_out<<<NE * 16 / 256, 256, 0, stream>>>(pool, invc, cnt, dflag,
                                                 misc + 1280, misc + 1792, misc + 1808, d_out);
        return;
    }

    // ---------- fallback carve (R4 layout, ~155 MB) ----------
    p = (char*)d_ws;
    float* fR  = (float*)carve((size_t)NE * 64 * 4);
    float* fC  = (float*)carve((size_t)NE * 64 * 4);
    float* A1  = (float*)carve((size_t)NE * 32 * 4);
    float* B1  = (float*)carve((size_t)NE * 32 * 4);
    float* A2  = (float*)carve((size_t)NE * 64 * 4);
    float* B2  = (float*)carve((size_t)NE * 64 * 4);
    float* A3  = (float*)carve((size_t)NE * 32 * 4);
    float* B3  = (float*)carve((size_t)NE * 32 * 4);
    cnt   = (int*)carve((size_t)NE * 4);
    invc  = (float*)carve((size_t)NE * 4);
    Wbuf  = (float*)carve((size_t)WTOT * 4);
    misc  = (float*)carve(2048 * 4);
    dflag = (int*)carve(64 * 4);
    float* fpool = fR;

    hipMemsetAsync(misc, 0, 2048 * 4, stream);
    hipMemsetAsync(cnt, 0, (size_t)NE * 4, stream);
    hipMemsetAsync(fR, 0, (size_t)NE * 64 * 4, stream);
    hipMemsetAsync(fC, 0, (size_t)NE * 64 * 4, stream);
    k_detect<<<1, 64, 0, stream>>>((const unsigned*)values, dflag);
    k_convW<<<(WTOT + 255) / 256, 256, 0, stream>>>(d_in[4], d_in[5], d_in[6], d_in[7],
                                                    d_in[8], d_in[9], d_in[10], d_in[11],
                                                    d_in[12], d_in[13], dflag, Wbuf);
    k_prep<<<1, 64, 0, stream>>>(misc);
    k_count<<<NZ / 256, 256, 0, stream>>>(row, cnt);
    k_invcnt<<<(NE + 255) / 256, 256, 0, stream>>>(cnt, invc);
    k_tm<<<512, 256, 0, stream>>>(values, dflag, misc + 960);

    k_seg1<<<NZ * 4 / 256, 256, 0, stream>>>(values, dflag, row, col, fR, fC);
    k_node<16, 32, 32><<<NE / 32, 256, 0, stream>>>(fR, fC, invc, misc + 0, Wbuf + W1O, A1, B1);
    k_const<<<1, 64, 0, stream>>>(Wbuf + W1O, Wbuf + B1O, misc + 960, 1, misc + 1024, 16, 32);
    hipMemsetAsync(fR, 0, (size_t)NE * 64 * 4, stream);
    hipMemsetAsync(fC, 0, (size_t)NE * 64 * 4, stream);
    k_l1<<<2048, 256, 0, stream>>>(values, dflag, row, col, perm, Wbuf, misc + 1024,
                                   A1, B1, fR, fC, misc + 512, misc + 768);
    k_fin<<<1, 64, 0, stream>>>(misc + 512, misc + 768, misc + 128, 32);

    k_node<32, 64, 64><<<NE / 16, 256, 0, stream>>>(fR, fC, invc, misc + 128, Wbuf + W2O, A2, B2);
    k_const<<<1, 64, 0, stream>>>(Wbuf + W2O, Wbuf + B2O, misc + 960, 0, misc + 1088, 32, 64);
    hipMemsetAsync(fR, 0, (size_t)NE * 64 * 4, stream);
    hipMemsetAsync(fC, 0, (size_t)NE * 64 * 4, stream);
    k_pair<false><<<2048, 256, 0, stream>>>(values, dflag, row, col, perm, Wbuf,
                                            misc + 1024, A1, B1, misc + 128,
                                            misc + 1088, A2, B2, misc + 256,
                                            misc + 1152, A1, B1,
                                            fR, fC, misc + 576, misc + 832);
    k_fin<<<1, 64, 0, stream>>>(misc + 576, misc + 832, misc + 256, 64);

    k_node<64, 32, 32><<<NE / 32, 256, 0, stream>>>(fR, fC, invc, misc + 256, Wbuf + W3O, A3, B3);
    k_const<<<1, 64, 0, stream>>>(Wbuf + W3O, Wbuf + B3O, misc + 960, 0, misc + 1152, 64, 32);
    hipMemsetAsync(fpool, 0, (size_t)NE * 32 * 4, stream);
    k_pair<true><<<2048, 256, 0, stream>>>(values, dflag, row, col, perm, Wbuf,
                                           misc + 1024, A1, B1, misc + 128,
                                           misc + 1088, A2, B2, misc + 256,
                                           misc + 1152, A3, B3,
                                           fpool, nullptr, misc + 640, misc + 896);
    k_fin<<<1, 64, 0, stream>>>(misc + 640, misc + 896, misc + 384, 32);

    k_head<<<1, 512, 0, stream>>>(Wbuf, misc + 384, misc + 1280, misc + 1792, misc + 1808);
    k_out<<<NE * 16 / 256, 256, 0, stream>>>(fpool, invc, cnt, dflag,
                                             misc + 1280, misc + 1792, misc + 1808, d_out);
}

// Round 6
// 1224.492 us; speedup vs baseline: 1.9637x; 1.9637x over previous
//
#include <hip/hip_runtime.h>
#include <hip/hip_bf16.h>

// Problem constants (fixed by the reference)
constexpr int NE   = 100000;     // entities
constexpr int NZ   = 1600000;    // nnz (divisible by 256)
constexpr int NZH  = NZ / 2;
constexpr int NSB  = (NE + 1023) / 1024;   // 98 scan blocks
constexpr float EPSV = 1e-5f;

// f32 weight-scratch layout (element offsets)
constexpr int W1O = 0,     B1O = 3584,  W2O = 3616,  B2O = 17952, W3O = 18016,
              B3O = 32352, WPO = 32384, BPO = 32896, WLO = 32912, BLO = 33168,
              WTOT = 33184;

typedef __hip_bfloat16 bf16;
typedef __attribute__((ext_vector_type(8))) short short8v;   // 8 bf16 (4 VGPRs)
typedef __attribute__((ext_vector_type(4))) float f32x4;     // MFMA C/D
#define MFMA_B16(A_, B_, C_) __builtin_amdgcn_mfma_f32_16x16x32_bf16((A_), (B_), (C_), 0, 0, 0)
#define PARTNER(i_) (((i_) < NZH) ? (i_) + NZH : (i_) - NZH)

// ---------- helpers ----------
__device__ __forceinline__ float4 ld_bf4(const bf16* p) {
    uint2 u = *(const uint2*)p;
    float4 r;
    r.x = __uint_as_float(u.x << 16);
    r.y = __uint_as_float(u.x & 0xffff0000u);
    r.z = __uint_as_float(u.y << 16);
    r.w = __uint_as_float(u.y & 0xffff0000u);
    return r;
}
__device__ __forceinline__ void cv_bf8(uint4 u, float4& lo, float4& hi) {
    lo.x = __uint_as_float(u.x << 16); lo.y = __uint_as_float(u.x & 0xffff0000u);
    lo.z = __uint_as_float(u.y << 16); lo.w = __uint_as_float(u.y & 0xffff0000u);
    hi.x = __uint_as_float(u.z << 16); hi.y = __uint_as_float(u.z & 0xffff0000u);
    hi.z = __uint_as_float(u.w << 16); hi.w = __uint_as_float(u.w & 0xffff0000u);
}
__device__ __forceinline__ void ld_bf8v(const bf16* p, float4& lo, float4& hi) {
    cv_bf8(*(const uint4*)p, lo, hi);
}
__device__ __forceinline__ float2 ld_bf2(const bf16* p) {
    unsigned u = *(const unsigned*)p;
    float2 r;
    r.x = __uint_as_float(u << 16);
    r.y = __uint_as_float(u & 0xffff0000u);
    return r;
}
__device__ __forceinline__ void st_bf4(bf16* p, float4 v) {
    __hip_bfloat162 lo = __float22bfloat162_rn(make_float2(v.x, v.y));
    __hip_bfloat162 hi = __float22bfloat162_rn(make_float2(v.z, v.w));
    uint2 u;
    u.x = *reinterpret_cast<unsigned int*>(&lo);
    u.y = *reinterpret_cast<unsigned int*>(&hi);
    *(uint2*)p = u;
}
__device__ __forceinline__ void st_bf8(bf16* p, float4 a, float4 b) {
    __hip_bfloat162 p0 = __float22bfloat162_rn(make_float2(a.x, a.y));
    __hip_bfloat162 p1 = __float22bfloat162_rn(make_float2(a.z, a.w));
    __hip_bfloat162 p2 = __float22bfloat162_rn(make_float2(b.x, b.y));
    __hip_bfloat162 p3 = __float22bfloat162_rn(make_float2(b.z, b.w));
    uint4 u;
    u.x = *reinterpret_cast<unsigned int*>(&p0);
    u.y = *reinterpret_cast<unsigned int*>(&p1);
    u.z = *reinterpret_cast<unsigned int*>(&p2);
    u.w = *reinterpret_cast<unsigned int*>(&p3);
    *(uint4*)p = u;
}
__device__ __forceinline__ float fin1(float v) { return (fabsf(v) < 1e30f) ? v : 0.f; }
__device__ __forceinline__ float4 fin4(float4 v) {
    v.x = fin1(v.x); v.y = fin1(v.y); v.z = fin1(v.z); v.w = fin1(v.w);
    return v;
}
__device__ __forceinline__ float4 ld_x4(const void* p, int flag, size_t q4) {
    if (flag) return ld_bf4((const bf16*)p + q4 * 4);
    return *((const float4*)p + q4);
}
__device__ __forceinline__ float4 relu4s(float4 x, float4 a, float4 b, const float* c) {
    float4 r;
    r.x = fmaxf(x.x + a.x + b.x + c[0], 0.f);
    r.y = fmaxf(x.y + a.y + b.y + c[1], 0.f);
    r.z = fmaxf(x.z + a.z + b.z + c[2], 0.f);
    r.w = fmaxf(x.w + a.w + b.w + c[3], 0.f);
    return r;
}
// split 8 floats into bf16 hi + lo residual fragments
__device__ __forceinline__ void split8(const float* x, short8v& hi, short8v& lo) {
    #pragma unroll
    for (int i = 0; i < 8; i++) {
        bf16 h = __float2bfloat16(x[i]);
        float r = x[i] - __bfloat162float(h);
        bf16 l2 = __float2bfloat16(r);
        hi[i] = *reinterpret_cast<short*>(&h);
        lo[i] = *reinterpret_cast<short*>(&l2);
    }
}
#define BF2F(h) __bfloat162float(h)
#define ADD4(D_, A_) do { (D_).x += (A_).x; (D_).y += (A_).y; (D_).z += (A_).z; (D_).w += (A_).w; } while(0)
#define SQ4(D_, A_) do { (D_).x += (A_).x*(A_).x; (D_).y += (A_).y*(A_).y; \
                         (D_).z += (A_).z*(A_).z; (D_).w += (A_).w*(A_).w; } while(0)
#define FMA4S(D_, S_, W_) do { (D_).x += (S_)*(W_).x; (D_).y += (S_)*(W_).y; \
                               (D_).z += (S_)*(W_).z; (D_).w += (S_)*(W_).w; } while(0)

// ---------- dtype detection ----------
__global__ void k_detect(const unsigned* __restrict__ v, int* __restrict__ dflag) {
    int lane = threadIdx.x;
    unsigned w = v[lane * 7 + 1];
    unsigned b = (w >> 8) & 0xFFu;
    bool plausible = (b >= 0x36u && b <= 0x41u) || (b >= 0xB6u && b <= 0xC1u);
    unsigned long long m = __ballot(plausible);
    if (lane == 0) {
        dflag[0] = (__popcll(m) >= 32) ? 1 : 0;   // 1 = bf16, 0 = f32
        dflag[1] = 0;                              // perm-structure violation flag
    }
}

__global__ void k_convW(const void* W1, const void* b1, const void* W2, const void* b2,
                        const void* W3, const void* b3, const void* Wp, const void* bp,
                        const void* Wl, const void* bl, const int* __restrict__ dflag,
                        float* __restrict__ Wb) {
    int t = blockIdx.x * 256 + threadIdx.x;
    if (t >= WTOT) return;
    int flag = dflag[0];
    const void* src; int l;
    if      (t < B1O) { src = W1; l = t; }
    else if (t < W2O) { src = b1; l = t - B1O; }
    else if (t < B2O) { src = W2; l = t - W2O; }
    else if (t < W3O) { src = b2; l = t - B2O; }
    else if (t < B3O) { src = W3; l = t - W3O; }
    else if (t < WPO) { src = b3; l = t - B3O; }
    else if (t < BPO) { src = Wp; l = t - WPO; }
    else if (t < WLO) { src = bp; l = t - BPO; }
    else if (t < BLO) { src = Wl; l = t - WLO; }
    else              { src = bl; l = t - BLO; }
    float v = flag ? BF2F(((const bf16*)src)[l]) : ((const float*)src)[l];
    Wb[t] = fin1(v);
}

// ---------- shared small kernels ----------
__global__ void k_prep(float* misc) {              // rs0 = 1 (m0=0 via memset)
    int t = threadIdx.x;
    if (t < 64) misc[64 + t] = 1.0f;
}

__global__ void k_count(const int* __restrict__ row, int* __restrict__ cnt) {
    int i = blockIdx.x * 256 + threadIdx.x;
    atomicAdd(&cnt[row[i]], 1);
}

__global__ void k_invcnt(const int* __restrict__ cnt, float* __restrict__ invc) {
    int n = blockIdx.x * 256 + threadIdx.x;
    if (n < NE) invc[n] = 1.0f / (float)max(cnt[n], 1);
}

__global__ void k_tm(const void* __restrict__ xv, const int* __restrict__ dflag,
                     float* __restrict__ tmsum) {
    int flag = dflag[0];
    __shared__ float s[16];
    if (threadIdx.x < 16) s[threadIdx.x] = 0.f;
    __syncthreads();
    float4 acc = {0, 0, 0, 0};
    int q = (blockIdx.x * 256 + threadIdx.x) & 3;
    for (size_t i = (size_t)blockIdx.x * 256 + threadIdx.x; i < (size_t)NZ * 4;
         i += (size_t)gridDim.x * 256) {
        float4 v = fin4(ld_x4(xv, flag, i));
        ADD4(acc, v);
    }
    atomicAdd(&s[q * 4 + 0], acc.x); atomicAdd(&s[q * 4 + 1], acc.y);
    atomicAdd(&s[q * 4 + 2], acc.z); atomicAdd(&s[q * 4 + 3], acc.w);
    __syncthreads();
    if (threadIdx.x < 16) unsafeAtomicAdd(&tmsum[threadIdx.x], s[threadIdx.x]);
}

__global__ void k_const(const float* __restrict__ W, const float* __restrict__ bias,
                        const float* __restrict__ tmsum, int use_tm, float* __restrict__ c0,
                        int CIN, int COUT) {
    int co = threadIdx.x;
    if (co < COUT) {
        float v = bias[co];
        if (use_tm)
            for (int ci = 0; ci < CIN; ci++)
                v += tmsum[ci] * (1.0f / NZ) * W[(6 * CIN + ci) * COUT + co];
        c0[co] = v;
    }
}

__global__ void k_fin(const float* __restrict__ S, const float* __restrict__ S2,
                      float* __restrict__ mout, int COUT) {
    int c = threadIdx.x;
    if (c < COUT) {
        float m = S[c] * (1.0f / NZ);
        float var = S2[c] * (1.0f / NZ) - m * m;
        mout[c] = m;
        mout[64 + c] = rsqrtf(fmaxf(var, 0.f) + EPSV);
    }
}

__global__ void k_head(const float* __restrict__ Wb, const float* __restrict__ mp3,
                       float* __restrict__ Wf2, float* __restrict__ base,
                       float* __restrict__ corr) {
    __shared__ float sWW[512];
    int t = threadIdx.x;
    int ci = t >> 4, o = t & 15;
    float s = 0.f;
    for (int k = 0; k < 16; k++)
        s += Wb[WPO + ci * 16 + k] * Wb[WLO + k * 16 + o];
    float m = mp3[ci], rs = mp3[64 + ci];
    Wf2[t] = rs * s;
    sWW[t] = m * rs * s;
    __syncthreads();
    if (t < 16) {
        float v = Wb[BLO + t];
        for (int k = 0; k < 16; k++) v += Wb[BPO + k] * Wb[WLO + k * 16 + t];
        base[t] = v;
        float cr = 0.f;
        for (int c = 0; c < 32; c++) cr += sWW[c * 16 + t];
        corr[t] = cr;
    }
}

__global__ void k_out(const float* __restrict__ pool, const float* __restrict__ invc,
                      const int* __restrict__ cnt, const int* __restrict__ dflag,
                      const float* __restrict__ Wf2, const float* __restrict__ base,
                      const float* __restrict__ corr, void* __restrict__ out) {
    int flag = dflag[0];
    int t = blockIdx.x * 256 + threadIdx.x;
    int n = t >> 4, o = t & 15;
    float dot = 0.f;
    #pragma unroll 4
    for (int c = 0; c < 32; c++) dot += pool[(size_t)n * 32 + c] * Wf2[c * 16 + o];
    float corr_t = (cnt[n] > 0) ? corr[o] : 0.f;
    float v = base[o] - corr_t + invc[n] * dot;
    if (flag) ((bf16*)out)[t] = __float2bfloat16(v);
    else      ((float*)out)[t] = v;
}

// ==================== FAST PATH (bucketed, atomic-free) ====================

// multi-block exclusive scan of cnt[NE] -> off[NE+1]
__global__ __launch_bounds__(1024) void k_scan1(const int* __restrict__ cnt,
                                                int* __restrict__ blks) {
    __shared__ int s[1024];
    int idx = blockIdx.x * 1024 + threadIdx.x;
    s[threadIdx.x] = (idx < NE) ? cnt[idx] : 0;
    __syncthreads();
    #pragma unroll
    for (int d = 512; d > 0; d >>= 1) {
        if (threadIdx.x < d) s[threadIdx.x] += s[threadIdx.x + d];
        __syncthreads();
    }
    if (threadIdx.x == 0) blks[blockIdx.x] = s[0];
}

__global__ void k_scan2(const int* __restrict__ blks, int* __restrict__ blkoff,
                        int* __restrict__ off) {
    __shared__ int s[128];
    int t = threadIdx.x;
    int v = (t < NSB) ? blks[t] : 0;
    s[t] = v;
    __syncthreads();
    #pragma unroll
    for (int d = 1; d < 128; d <<= 1) {
        int a = (t >= d) ? s[t - d] : 0;
        __syncthreads();
        s[t] += a;
        __syncthreads();
    }
    if (t < NSB) blkoff[t] = s[t] - v;
    if (t == 127) off[NE] = s[127];   // == NZ
}

__global__ __launch_bounds__(1024) void k_scan3(const int* __restrict__ cnt,
                                                const int* __restrict__ blkoff,
                                                int* __restrict__ off) {
    __shared__ int s[1024];
    int idx = blockIdx.x * 1024 + threadIdx.x;
    int t = threadIdx.x;
    int v = (idx < NE) ? cnt[idx] : 0;
    s[t] = v;
    __syncthreads();
    #pragma unroll
    for (int d = 1; d < 1024; d <<= 1) {
        int a = (t >= d) ? s[t - d] : 0;
        __syncthreads();
        s[t] += a;
        __syncthreads();
    }
    if (idx < NE) off[idx] = blkoff[blockIdx.x] + s[t] - v;
}

__global__ void k_scatter(const int* __restrict__ row, const int* __restrict__ perm,
                          const int* __restrict__ off,
                          int* __restrict__ tmp, int* __restrict__ bucket,
                          int* __restrict__ dflag) {
    int e = blockIdx.x * 256 + threadIdx.x;        // grid exactly NZ/256
    int n = row[e];
    int rk = atomicAdd(&tmp[n], 1);
    bucket[off[n] + rk] = e;
    // verify the symmetrization structure perm[e] == e +- NZ/2 (reference construction).
    if (perm[e] != PARTNER(e)) dflag[1] = 1;       // benign race: any write sets
}

// S0: node-gather raw sums of values (16 ch); 4 lanes/node; unroll x2; arithmetic partner.
// Also produces the global tm sum (folded k_tm).
__global__ __launch_bounds__(256) void k_gsv(const void* __restrict__ xv,
                                             const int* __restrict__ dflag,
                                             const int* __restrict__ bucket,
                                             const int* __restrict__ off,
                                             const int* __restrict__ perm,
                                             float* __restrict__ rawR, float* __restrict__ rawC,
                                             float* __restrict__ tmsum) {
    __shared__ float red[16];
    if (threadIdx.x < 16) red[threadIdx.x] = 0.f;
    __syncthreads();
    int flag = dflag[0];
    int g = blockIdx.x * 64 + (threadIdx.x >> 2);
    int q = threadIdx.x & 3;
    float4 r4 = {0,0,0,0}, c4 = {0,0,0,0};
    int e0 = 0, e1 = 0;
    if (g < NE) { e0 = off[g]; e1 = off[g + 1]; }
    if (dflag[1] == 0) {
        int idx = e0;
        for (; idx + 1 < e1; idx += 2) {
            int i0 = bucket[idx], i1 = bucket[idx + 1];
            int p0 = PARTNER(i0), p1 = PARTNER(i1);
            float4 va0 = fin4(ld_x4(xv, flag, (size_t)i0 * 4 + q));
            float4 vb0 = fin4(ld_x4(xv, flag, (size_t)p0 * 4 + q));
            float4 va1 = fin4(ld_x4(xv, flag, (size_t)i1 * 4 + q));
            float4 vb1 = fin4(ld_x4(xv, flag, (size_t)p1 * 4 + q));
            ADD4(r4, va0); ADD4(c4, vb0);
            ADD4(r4, va1); ADD4(c4, vb1);
        }
        if (idx < e1) {
            int i = bucket[idx], p = PARTNER(i);
            float4 va = fin4(ld_x4(xv, flag, (size_t)i * 4 + q));
            float4 vb = fin4(ld_x4(xv, flag, (size_t)p * 4 + q));
            ADD4(r4, va); ADD4(c4, vb);
        }
    } else {
        for (int idx = e0; idx < e1; idx++) {
            int i = bucket[idx], p = perm[i];
            float4 va = fin4(ld_x4(xv, flag, (size_t)i * 4 + q));
            float4 vb = fin4(ld_x4(xv, flag, (size_t)p * 4 + q));
            ADD4(r4, va); ADD4(c4, vb);
        }
    }
    if (g < NE) {
        *(float4*)(rawR + (size_t)g * 64 + q * 4) = r4;
        *(float4*)(rawC + (size_t)g * 64 + q * 4) = c4;
    }
    atomicAdd(&red[q * 4 + 0], r4.x); atomicAdd(&red[q * 4 + 1], r4.y);
    atomicAdd(&red[q * 4 + 2], r4.z); atomicAdd(&red[q * 4 + 3], r4.w);
    __syncthreads();
    if (threadIdx.x < 16) unsafeAtomicAdd(&tmsum[threadIdx.x], red[threadIdx.x]);
}

// node kernel -> bf16 A/B tables; rm=(raw*invc - m*[cnt>0])*rs
template<int CIN, int COUT>
__global__ __launch_bounds__(256) void k_nodeb(const float* __restrict__ inR,
                                               const float* __restrict__ inC,
                                               const float* __restrict__ invc,
                                               const int* __restrict__ cnt,
                                               const float* __restrict__ mp,
                                               const float* __restrict__ W,
                                               bf16* __restrict__ outA, bf16* __restrict__ outB) {
    constexpr int QC = COUT / 4;
    constexpr int G  = 256 / QC;
    __shared__ __align__(16) float W2s[CIN*COUT], W3s[CIN*COUT], W4s[CIN*COUT], W5s[CIN*COUT];
    __shared__ __align__(16) float rmS[G*CIN], cmS[G*CIN];
    for (int i = threadIdx.x; i < CIN * COUT; i += 256) {
        W2s[i] = W[2 * CIN * COUT + i];
        W3s[i] = W[3 * CIN * COUT + i];
        W4s[i] = W[4 * CIN * COUT + i];
        W5s[i] = W[5 * CIN * COUT + i];
    }
    int n0 = blockIdx.x * G;
    for (int i = threadIdx.x; i < G * CIN; i += 256) {
        int g = i / CIN, ci = i % CIN;
        int n = n0 + g;
        float ic = invc[n];
        float mt = (cnt[n] > 0) ? mp[ci] : 0.f;
        float rs = mp[64 + ci];
        rmS[i] = (inR[(size_t)n * 64 + ci] * ic - mt) * rs;
        cmS[i] = (inC[(size_t)n * 64 + ci] * ic - mt) * rs;
    }
    __syncthreads();
    int g = threadIdx.x / QC, q = threadIdx.x % QC;
    int n = n0 + g;
    float4 a = {0,0,0,0}, b = {0,0,0,0};
    #pragma unroll 4
    for (int ci = 0; ci < CIN; ci++) {
        float rm = rmS[g * CIN + ci], cm = cmS[g * CIN + ci];
        float4 w2 = *(const float4*)(W2s + ci * COUT + q * 4);
        float4 w3 = *(const float4*)(W3s + ci * COUT + q * 4);
        float4 w4 = *(const float4*)(W4s + ci * COUT + q * 4);
        float4 w5 = *(const float4*)(W5s + ci * COUT + q * 4);
        FMA4S(a, rm, w2); FMA4S(a, cm, w4);
        FMA4S(b, rm, w3); FMA4S(b, cm, w5);
    }
    st_bf4(outA + (size_t)n * COUT + q * 4, a);
    st_bf4(outB + (size_t)n * COUT + q * 4, b);
}

// k_l1n: entry-parallel (quad/entry), writes h1 bf16, stats. (legacy fast path)
__global__ __launch_bounds__(256) void k_l1n(const void* __restrict__ xv,
                                             const int* __restrict__ dflag,
                                             const int* __restrict__ row, const int* __restrict__ col,
                                             const int* __restrict__ perm,
                                             const float* __restrict__ Wb,
                                             const float* __restrict__ c01,
                                             const bf16* __restrict__ A1b, const bf16* __restrict__ B1b,
                                             bf16* __restrict__ h1,
                                             float* __restrict__ Ssum, float* __restrict__ S2sum) {
    const int flag = dflag[0];
    __shared__ __align__(16) float W10s[512], W11s[512];
    __shared__ __align__(16) float c01s[32];
    __shared__ float red[64];
    for (int i = threadIdx.x; i < 512; i += 256) {
        W10s[i] = Wb[W1O + i];
        W11s[i] = Wb[W1O + 512 + i];
    }
    if (threadIdx.x < 32) c01s[threadIdx.x] = c01[threadIdx.x];
    if (threadIdx.x < 64) red[threadIdx.x] = 0.f;
    __syncthreads();
    const int e = blockIdx.x * 64 + (threadIdx.x >> 2);   // grid exactly NZ/64
    const int j = threadIdx.x & 3;
    const int o = j * 8;
    int r = row[e], c = col[e], p = perm[e];
    float xe[16], xp[16];
    #pragma unroll
    for (int i4 = 0; i4 < 4; i4++) {
        float4 va = fin4(ld_x4(xv, flag, (size_t)e * 4 + i4));
        float4 vb = fin4(ld_x4(xv, flag, (size_t)p * 4 + i4));
        xe[i4*4+0]=va.x; xe[i4*4+1]=va.y; xe[i4*4+2]=va.z; xe[i4*4+3]=va.w;
        xp[i4*4+0]=vb.x; xp[i4*4+1]=vb.y; xp[i4*4+2]=vb.z; xp[i4*4+3]=vb.w;
    }
    float4 alo = ld_bf4(A1b + (size_t)r * 32 + o);
    float4 ahi = ld_bf4(A1b + (size_t)r * 32 + o + 4);
    float4 blo = ld_bf4(B1b + (size_t)c * 32 + o);
    float4 bhi = ld_bf4(B1b + (size_t)c * 32 + o + 4);
    float ae[8];
    ae[0]=c01s[o+0]+alo.x+blo.x; ae[1]=c01s[o+1]+alo.y+blo.y;
    ae[2]=c01s[o+2]+alo.z+blo.z; ae[3]=c01s[o+3]+alo.w+blo.w;
    ae[4]=c01s[o+4]+ahi.x+bhi.x; ae[5]=c01s[o+5]+ahi.y+bhi.y;
    ae[6]=c01s[o+6]+ahi.z+bhi.z; ae[7]=c01s[o+7]+ahi.w+bhi.w;
    #pragma unroll
    for (int ci = 0; ci < 16; ci++) {
        const float* w0 = W10s + ci * 32 + o;
        const float* w1 = W11s + ci * 32 + o;
        float a = xe[ci], b = xp[ci];
        #pragma unroll
        for (int u = 0; u < 8; u++) ae[u] += a * w0[u] + b * w1[u];
    }
    float4 hlo, hhi;
    hlo.x=fmaxf(ae[0],0.f); hlo.y=fmaxf(ae[1],0.f); hlo.z=fmaxf(ae[2],0.f); hlo.w=fmaxf(ae[3],0.f);
    hhi.x=fmaxf(ae[4],0.f); hhi.y=fmaxf(ae[5],0.f); hhi.z=fmaxf(ae[6],0.f); hhi.w=fmaxf(ae[7],0.f);
    st_bf4(h1 + (size_t)e * 32 + o, hlo);
    st_bf4(h1 + (size_t)e * 32 + o + 4, hhi);
    #pragma unroll
    for (int u = 0; u < 8; u++) {
        float h = fmaxf(ae[u], 0.f);
        atomicAdd(&red[o + u], h);
        atomicAdd(&red[32 + o + u], h * h);
    }
    __syncthreads();
    if (threadIdx.x < 32) {
        unsafeAtomicAdd(&Ssum[threadIdx.x], red[threadIdx.x]);
        unsafeAtomicAdd(&S2sum[threadIdx.x], red[32 + threadIdx.x]);
    }
}

// S1: node-gather raw sums of h1 (32 ch); 4 lanes/node; unroll x4; arithmetic partner.
template<bool STATS>
__global__ __launch_bounds__(256) void k_gsh1(const bf16* __restrict__ h1,
                                              const int* __restrict__ bucket,
                                              const int* __restrict__ off,
                                              const int* __restrict__ perm,
                                              const int* __restrict__ dflag,
                                              float* __restrict__ rawR, float* __restrict__ rawC,
                                              float* __restrict__ Ssum, float* __restrict__ S2sum) {
    __shared__ float red[64];
    if (STATS) {
        if (threadIdx.x < 64) red[threadIdx.x] = 0.f;
        __syncthreads();
    }
    int g = blockIdx.x * 64 + (threadIdx.x >> 2);   // grid ceil(NE/64)
    int q = threadIdx.x & 3;
    float4 ra = {0,0,0,0}, rb = {0,0,0,0}, ca = {0,0,0,0}, cb = {0,0,0,0};
    float4 sa = {0,0,0,0}, sb = {0,0,0,0};
    int e0 = 0, e1 = 0;
    if (g < NE) { e0 = off[g]; e1 = off[g + 1]; }
    const bf16* hk = h1 + q * 8;
    if (dflag[1] == 0) {
        int idx = e0;
        for (; idx + 3 < e1; idx += 4) {
            int i0 = bucket[idx],     i1 = bucket[idx + 1];
            int i2 = bucket[idx + 2], i3 = bucket[idx + 3];
            uint4 u0 = *(const uint4*)(hk + (size_t)i0 * 32);
            uint4 v0 = *(const uint4*)(hk + (size_t)PARTNER(i0) * 32);
            uint4 u1 = *(const uint4*)(hk + (size_t)i1 * 32);
            uint4 v1 = *(const uint4*)(hk + (size_t)PARTNER(i1) * 32);
            uint4 u2 = *(const uint4*)(hk + (size_t)i2 * 32);
            uint4 v2 = *(const uint4*)(hk + (size_t)PARTNER(i2) * 32);
            uint4 u3 = *(const uint4*)(hk + (size_t)i3 * 32);
            uint4 v3 = *(const uint4*)(hk + (size_t)PARTNER(i3) * 32);
            float4 L, H;
            cv_bf8(u0, L, H); ADD4(ra, L); ADD4(rb, H); if (STATS) { SQ4(sa, L); SQ4(sb, H); }
            cv_bf8(u1, L, H); ADD4(ra, L); ADD4(rb, H); if (STATS) { SQ4(sa, L); SQ4(sb, H); }
            cv_bf8(u2, L, H); ADD4(ra, L); ADD4(rb, H); if (STATS) { SQ4(sa, L); SQ4(sb, H); }
            cv_bf8(u3, L, H); ADD4(ra, L); ADD4(rb, H); if (STATS) { SQ4(sa, L); SQ4(sb, H); }
            cv_bf8(v0, L, H); ADD4(ca, L); ADD4(cb, H);
            cv_bf8(v1, L, H); ADD4(ca, L); ADD4(cb, H);
            cv_bf8(v2, L, H); ADD4(ca, L); ADD4(cb, H);
            cv_bf8(v3, L, H); ADD4(ca, L); ADD4(cb, H);
        }
        for (; idx < e1; idx++) {
            int i = bucket[idx], p = PARTNER(i);
            float4 aL, aH, bL, bH;
            ld_bf8v(hk + (size_t)i * 32, aL, aH);
            ld_bf8v(hk + (size_t)p * 32, bL, bH);
            ADD4(ra, aL); ADD4(rb, aH); ADD4(ca, bL); ADD4(cb, bH);
            if (STATS) { SQ4(sa, aL); SQ4(sb, aH); }
        }
    } else {
        for (int idx = e0; idx < e1; idx++) {
            int i = bucket[idx], p = perm[i];
            float4 aL, aH, bL, bH;
            ld_bf8v(hk + (size_t)i * 32, aL, aH);
            ld_bf8v(hk + (size_t)p * 32, bL, bH);
            ADD4(ra, aL); ADD4(rb, aH); ADD4(ca, bL); ADD4(cb, bH);
            if (STATS) { SQ4(sa, aL); SQ4(sb, aH); }
        }
    }
    if (g < NE) {
        *(float4*)(rawR + (size_t)g * 64 + q * 8) = ra;
        *(float4*)(rawR + (size_t)g * 64 + q * 8 + 4) = rb;
        *(float4*)(rawC + (size_t)g * 64 + q * 8) = ca;
        *(float4*)(rawC + (size_t)g * 64 + q * 8 + 4) = cb;
    }
    if (STATS) {
        int o = q * 8;
        atomicAdd(&red[o+0], ra.x); atomicAdd(&red[o+1], ra.y);
        atomicAdd(&red[o+2], ra.z); atomicAdd(&red[o+3], ra.w);
        atomicAdd(&red[o+4], rb.x); atomicAdd(&red[o+5], rb.y);
        atomicAdd(&red[o+6], rb.z); atomicAdd(&red[o+7], rb.w);
        atomicAdd(&red[32+o+0], sa.x); atomicAdd(&red[32+o+1], sa.y);
        atomicAdd(&red[32+o+2], sa.z); atomicAdd(&red[32+o+3], sa.w);
        atomicAdd(&red[32+o+4], sb.x); atomicAdd(&red[32+o+5], sb.y);
        atomicAdd(&red[32+o+6], sb.z); atomicAdd(&red[32+o+7], sb.w);
        __syncthreads();
        if (threadIdx.x < 32) {
            unsafeAtomicAdd(&Ssum[threadIdx.x], red[threadIdx.x]);
            unsafeAtomicAdd(&S2sum[threadIdx.x], red[32 + threadIdx.x]);
        }
    }
}

// ---------- MFMA path: weight folding ----------
template<int KH, int COUT>
__global__ void k_fold(const float* __restrict__ W, const float* __restrict__ mp,
                       const float* __restrict__ c0, bf16* __restrict__ Wfs,
                       float* __restrict__ c0f) {
    int t = blockIdx.x * 256 + threadIdx.x;     // grid = 16 blocks -> 4096 threads
    constexpr int NT = COUT / 16;
    int f = t >> 9, r = t & 511;
    int lane = r >> 3, j = r & 7;
    int kc = f / NT, nt = f % NT;
    int kl = ((lane >> 4) << 3) + j;
    int kg = kc * 32 + kl;
    int n  = nt * 16 + (lane & 15);
    float w = 0.f;
    if (kg < 2 * KH) {
        int k  = (kg < KH) ? kg : kg - KH;
        const float* Ws = W + ((kg < KH) ? 0 : KH * COUT);
        w = Ws[k * COUT + n] * mp[64 + k];
    }
    bf16 hi = __float2bfloat16(w);
    Wfs[t] = hi;
    Wfs[4096 + t] = __float2bfloat16(w - __bfloat162float(hi));
    if (t < COUT) {
        float acc = c0[t];
        for (int k2 = 0; k2 < KH; k2++)
            acc += (-mp[k2] * mp[64 + k2]) * (W[k2 * COUT + t] + W[KH * COUT + k2 * COUT + t]);
        c0f[t] = acc;
    }
}

// ---------- MFMA layer-1 edge pass ----------
__global__ __launch_bounds__(256) void k_l1e(const void* __restrict__ xv,
                                             const int* __restrict__ dflag,
                                             const int* __restrict__ row,
                                             const int* __restrict__ col,
                                             const int* __restrict__ perm,
                                             const bf16* __restrict__ Wfs,
                                             const float* __restrict__ c0f,
                                             const bf16* __restrict__ A1b,
                                             const bf16* __restrict__ B1b,
                                             bf16* __restrict__ h1) {
    __shared__ __align__(16) float tr[4][16 * 36];   // per-wave 16x32 transpose, pad 36
    __shared__ __align__(16) float c0s[32];
    if (threadIdx.x < 32) c0s[threadIdx.x] = c0f[threadIdx.x];
    const int flag = dflag[0];
    const int vio  = dflag[1];
    const int wv  = threadIdx.x >> 6;
    const int l   = threadIdx.x & 63;
    const int lr  = l & 15;
    const int lk  = l >> 4;          // k-group: k = lk*8 + j
    const int tb  = lk * 4;
    float* T = tr[wv];
    short8v bh[2], bl[2];
    bh[0] = *(const short8v*)(Wfs + 0 * 512 + l * 8);
    bh[1] = *(const short8v*)(Wfs + 1 * 512 + l * 8);
    bl[0] = *(const short8v*)(Wfs + 4096 + 0 * 512 + l * 8);
    bl[1] = *(const short8v*)(Wfs + 4096 + 1 * 512 + l * 8);
    const int eE = l >> 2, q = l & 3;
    const int kq = lk & 1;           // which 8-ch half of the 16 input channels
    __syncthreads();
    for (int bt = blockIdx.x; bt < NZ / 64; bt += gridDim.x) {
        const int te = bt * 64 + wv * 16;
        const int eA = te + lr;
        const int src = (lk < 2) ? eA : (vio ? perm[eA] : PARTNER(eA));
        float xr[8];
        float4 v0 = fin4(ld_x4(xv, flag, (size_t)src * 4 + kq * 2));
        float4 v1 = fin4(ld_x4(xv, flag, (size_t)src * 4 + kq * 2 + 1));
        xr[0]=v0.x; xr[1]=v0.y; xr[2]=v0.z; xr[3]=v0.w;
        xr[4]=v1.x; xr[5]=v1.y; xr[6]=v1.z; xr[7]=v1.w;
        short8v ah, al;
        split8(xr, ah, al);
        f32x4 ac0 = {0.f, 0.f, 0.f, 0.f};
        f32x4 ac1 = ac0;
        ac0 = MFMA_B16(ah, bh[0], ac0); ac1 = MFMA_B16(ah, bh[1], ac1);
        ac0 = MFMA_B16(ah, bl[0], ac0); ac1 = MFMA_B16(ah, bl[1], ac1);
        ac0 = MFMA_B16(al, bh[0], ac0); ac1 = MFMA_B16(al, bh[1], ac1);
        #pragma unroll
        for (int r = 0; r < 4; r++) {
            float* Tw = T + (tb + r) * 36 + lr;
            Tw[0] = ac0[r]; Tw[16] = ac1[r];
        }
        __syncthreads();
        {
            const int e  = te + eE;
            const int rr = row[e], cc = col[e];
            const float* Tp = T + eE * 36 + q * 8;
            const bf16* ap = A1b + (size_t)rr * 32 + q * 8;
            const bf16* bp = B1b + (size_t)cc * 32 + q * 8;
            const float* cp = c0s + q * 8;
            float4 hv0 = relu4s(*(const float4*)(Tp + 0), ld_bf4(ap + 0), ld_bf4(bp + 0), cp + 0);
            float4 hv1 = relu4s(*(const float4*)(Tp + 4), ld_bf4(ap + 4), ld_bf4(bp + 4), cp + 4);
            st_bf8(h1 + (size_t)e * 32 + q * 8, hv0, hv1);
        }
        __syncthreads();
    }
}

// ---------- MFMA layer-2 edge pass ----------
__global__ __launch_bounds__(256) void k_l2e(const bf16* __restrict__ h1,
                                             const int* __restrict__ row,
                                             const int* __restrict__ col,
                                             const int* __restrict__ perm,
                                             const int* __restrict__ dflag,
                                             const bf16* __restrict__ Wfs,
                                             const float* __restrict__ c0f,
                                             const bf16* __restrict__ A2b,
                                             const bf16* __restrict__ B2b,
                                             bf16* __restrict__ h2) {
    __shared__ __align__(16) float tr[4][16 * 68];   // per-wave 16x64 transpose, pad 68
    __shared__ __align__(16) float c0s[64];
    if (threadIdx.x < 64) c0s[threadIdx.x] = c0f[threadIdx.x];
    const int vio = dflag[1];
    const int wv  = threadIdx.x >> 6;
    const int l   = threadIdx.x & 63;
    const int lr  = l & 15;
    const int lk8 = (l >> 4) * 8;
    const int tb  = (l >> 4) * 4;
    float* T = tr[wv];
    short8v bh[8], bl[8];
    #pragma unroll
    for (int f = 0; f < 8; f++) {
        bh[f] = *(const short8v*)(Wfs + f * 512 + l * 8);
        bl[f] = *(const short8v*)(Wfs + 4096 + f * 512 + l * 8);
    }
    const int eE = l >> 2, q = l & 3;
    __syncthreads();
    for (int bt = blockIdx.x; bt < NZ / 64; bt += gridDim.x) {
        const int te = bt * 64 + wv * 16;
        const int eA = te + lr;
        const int pA = vio ? perm[eA] : PARTNER(eA);
        short8v a0 = *(const short8v*)(h1 + (size_t)eA * 32 + lk8);
        short8v a1 = *(const short8v*)(h1 + (size_t)pA * 32 + lk8);
        f32x4 ac0 = {0.f, 0.f, 0.f, 0.f};
        f32x4 ac1 = ac0, ac2 = ac0, ac3 = ac0;
        ac0 = MFMA_B16(a0, bh[0], ac0);  ac1 = MFMA_B16(a0, bh[1], ac1);
        ac2 = MFMA_B16(a0, bh[2], ac2);  ac3 = MFMA_B16(a0, bh[3], ac3);
        ac0 = MFMA_B16(a1, bh[4], ac0);  ac1 = MFMA_B16(a1, bh[5], ac1);
        ac2 = MFMA_B16(a1, bh[6], ac2);  ac3 = MFMA_B16(a1, bh[7], ac3);
        ac0 = MFMA_B16(a0, bl[0], ac0);  ac1 = MFMA_B16(a0, bl[1], ac1);
        ac2 = MFMA_B16(a0, bl[2], ac2);  ac3 = MFMA_B16(a0, bl[3], ac3);
        ac0 = MFMA_B16(a1, bl[4], ac0);  ac1 = MFMA_B16(a1, bl[5], ac1);
        ac2 = MFMA_B16(a1, bl[6], ac2);  ac3 = MFMA_B16(a1, bl[7], ac3);
        #pragma unroll
        for (int r = 0; r < 4; r++) {   // C: row=(l>>4)*4+r, col=lr (+16*nt)
            float* Tw = T + (tb + r) * 68 + lr;
            Tw[0] = ac0[r]; Tw[16] = ac1[r]; Tw[32] = ac2[r]; Tw[48] = ac3[r];
        }
        __syncthreads();
        {
            const int e  = te + eE;
            const int rr = row[e], cc = col[e];
            const float* Tp = T + eE * 68 + q * 16;
            const bf16* ap = A2b + (size_t)rr * 64 + q * 16;
            const bf16* bp = B2b + (size_t)cc * 64 + q * 16;
            const float* cp = c0s + q * 16;
            float4 hv0 = relu4s(*(const float4*)(Tp + 0),  ld_bf4(ap + 0),  ld_bf4(bp + 0),  cp + 0);
            float4 hv1 = relu4s(*(const float4*)(Tp + 4),  ld_bf4(ap + 4),  ld_bf4(bp + 4),  cp + 4);
            float4 hv2 = relu4s(*(const float4*)(Tp + 8),  ld_bf4(ap + 8),  ld_bf4(bp + 8),  cp + 8);
            float4 hv3 = relu4s(*(const float4*)(Tp + 12), ld_bf4(ap + 12), ld_bf4(bp + 12), cp + 12);
            st_bf8(h2 + (size_t)e * 64 + q * 16, hv0, hv1);
            st_bf8(h2 + (size_t)e * 64 + q * 16 + 8, hv2, hv3);
        }
        __syncthreads();
    }
}

// node-gather raw sums of h2 (64 ch) + layer-2 stats; 8 lanes/node; unroll x4; arithmetic partner.
__global__ __launch_bounds__(256) void k_gs64(const bf16* __restrict__ h2,
                                              const int* __restrict__ bucket,
                                              const int* __restrict__ off,
                                              const int* __restrict__ perm,
                                              const int* __restrict__ dflag,
                                              float* __restrict__ rawR, float* __restrict__ rawC,
                                              float* __restrict__ Ssum, float* __restrict__ S2sum) {
    __shared__ float red[128];
    if (threadIdx.x < 128) red[threadIdx.x] = 0.f;
    __syncthreads();
    int g = blockIdx.x * 32 + (threadIdx.x >> 3);   // grid exactly NE/32
    int k = threadIdx.x & 7;
    float4 ra = {0,0,0,0}, rb = {0,0,0,0}, ca = {0,0,0,0}, cb = {0,0,0,0};
    float4 sa = {0,0,0,0}, sb = {0,0,0,0};
    int e0 = off[g], e1 = off[g + 1];
    const bf16* hk = h2 + k * 8;
    if (dflag[1] == 0) {
        int idx = e0;
        for (; idx + 3 < e1; idx += 4) {
            int i0 = bucket[idx],     i1 = bucket[idx + 1];
            int i2 = bucket[idx + 2], i3 = bucket[idx + 3];
            uint4 u0 = *(const uint4*)(hk + (size_t)i0 * 64);
            uint4 v0 = *(const uint4*)(hk + (size_t)PARTNER(i0) * 64);
            uint4 u1 = *(const uint4*)(hk + (size_t)i1 * 64);
            uint4 v1 = *(const uint4*)(hk + (size_t)PARTNER(i1) * 64);
            uint4 u2 = *(const uint4*)(hk + (size_t)i2 * 64);
            uint4 v2 = *(const uint4*)(hk + (size_t)PARTNER(i2) * 64);
            uint4 u3 = *(const uint4*)(hk + (size_t)i3 * 64);
            uint4 v3 = *(const uint4*)(hk + (size_t)PARTNER(i3) * 64);
            float4 L, H;
            cv_bf8(u0, L, H); ADD4(ra, L); ADD4(rb, H); SQ4(sa, L); SQ4(sb, H);
            cv_bf8(u1, L, H); ADD4(ra, L); ADD4(rb, H); SQ4(sa, L); SQ4(sb, H);
            cv_bf8(u2, L, H); ADD4(ra, L); ADD4(rb, H); SQ4(sa, L); SQ4(sb, H);
            cv_bf8(u3, L, H); ADD4(ra, L); ADD4(rb, H); SQ4(sa, L); SQ4(sb, H);
            cv_bf8(v0, L, H); ADD4(ca, L); ADD4(cb, H);
            cv_bf8(v1, L, H); ADD4(ca, L); ADD4(cb, H);
            cv_bf8(v2, L, H); ADD4(ca, L); ADD4(cb, H);
            cv_bf8(v3, L, H); ADD4(ca, L); ADD4(cb, H);
        }
        for (; idx < e1; idx++) {
            int i = bucket[idx], p = PARTNER(i);
            float4 aL, aH, bL, bH;
            ld_bf8v(hk + (size_t)i * 64, aL, aH);
            ld_bf8v(hk + (size_t)p * 64, bL, bH);
            ADD4(ra, aL); ADD4(rb, aH); ADD4(ca, bL); ADD4(cb, bH);
            SQ4(sa, aL); SQ4(sb, aH);
        }
    } else {
        for (int idx = e0; idx < e1; idx++) {
            int i = bucket[idx], p = perm[i];
            float4 aL, aH, bL, bH;
            ld_bf8v(hk + (size_t)i * 64, aL, aH);
            ld_bf8v(hk + (size_t)p * 64, bL, bH);
            ADD4(ra, aL); ADD4(rb, aH); ADD4(ca, bL); ADD4(cb, bH);
            SQ4(sa, aL); SQ4(sb, aH);
        }
    }
    *(float4*)(rawR + (size_t)g * 64 + k * 8) = ra;
    *(float4*)(rawR + (size_t)g * 64 + k * 8 + 4) = rb;
    *(float4*)(rawC + (size_t)g * 64 + k * 8) = ca;
    *(float4*)(rawC + (size_t)g * 64 + k * 8 + 4) = cb;
    {
        int o = k * 8;
        atomicAdd(&red[o+0], ra.x); atomicAdd(&red[o+1], ra.y);
        atomicAdd(&red[o+2], ra.z); atomicAdd(&red[o+3], ra.w);
        atomicAdd(&red[o+4], rb.x); atomicAdd(&red[o+5], rb.y);
        atomicAdd(&red[o+6], rb.z); atomicAdd(&red[o+7], rb.w);
        atomicAdd(&red[64+o+0], sa.x); atomicAdd(&red[64+o+1], sa.y);
        atomicAdd(&red[64+o+2], sa.z); atomicAdd(&red[64+o+3], sa.w);
        atomicAdd(&red[64+o+4], sb.x); atomicAdd(&red[64+o+5], sb.y);
        atomicAdd(&red[64+o+6], sb.z); atomicAdd(&red[64+o+7], sb.w);
    }
    __syncthreads();
    if (threadIdx.x < 64) {
        unsafeAtomicAdd(&Ssum[threadIdx.x], red[threadIdx.x]);
        unsafeAtomicAdd(&S2sum[threadIdx.x], red[64 + threadIdx.x]);
    }
}

// ---------- MFMA layer-3 edge pass (writes h3; pooling in k_gsp) ----------
__global__ __launch_bounds__(256) void k_l3e(const bf16* __restrict__ h2,
                                             const int* __restrict__ row,
                                             const int* __restrict__ col,
                                             const int* __restrict__ perm,
                                             const int* __restrict__ dflag,
                                             const bf16* __restrict__ Wfs,
                                             const float* __restrict__ c0f,
                                             const bf16* __restrict__ A3b,
                                             const bf16* __restrict__ B3b,
                                             bf16* __restrict__ h3) {
    __shared__ __align__(16) float tr[4][16 * 36];   // per-wave 16x32 transpose, pad 36
    __shared__ __align__(16) float c0s[32];
    if (threadIdx.x < 32) c0s[threadIdx.x] = c0f[threadIdx.x];
    const int vio = dflag[1];
    const int wv  = threadIdx.x >> 6;
    const int l   = threadIdx.x & 63;
    const int lr  = l & 15;
    const int lk8 = (l >> 4) * 8;
    const int tb  = (l >> 4) * 4;
    float* T = tr[wv];
    short8v bh[8], bl[8];
    #pragma unroll
    for (int f = 0; f < 8; f++) {
        bh[f] = *(const short8v*)(Wfs + f * 512 + l * 8);
        bl[f] = *(const short8v*)(Wfs + 4096 + f * 512 + l * 8);
    }
    const int eE = l >> 2, q = l & 3;
    __syncthreads();
    for (int bt = blockIdx.x; bt < NZ / 64; bt += gridDim.x) {
        const int te = bt * 64 + wv * 16;
        const int eA = te + lr;
        const int pA = vio ? perm[eA] : PARTNER(eA);
        const bf16* he = h2 + (size_t)eA * 64;
        const bf16* hp = h2 + (size_t)pA * 64;
        short8v a0 = *(const short8v*)(he + lk8);
        short8v a1 = *(const short8v*)(he + 32 + lk8);
        short8v a2 = *(const short8v*)(hp + lk8);
        short8v a3 = *(const short8v*)(hp + 32 + lk8);
        f32x4 ac0 = {0.f, 0.f, 0.f, 0.f};
        f32x4 ac1 = ac0;
        ac0 = MFMA_B16(a0, bh[0], ac0); ac1 = MFMA_B16(a0, bh[1], ac1);
        ac0 = MFMA_B16(a1, bh[2], ac0); ac1 = MFMA_B16(a1, bh[3], ac1);
        ac0 = MFMA_B16(a2, bh[4], ac0); ac1 = MFMA_B16(a2, bh[5], ac1);
        ac0 = MFMA_B16(a3, bh[6], ac0); ac1 = MFMA_B16(a3, bh[7], ac1);
        ac0 = MFMA_B16(a0, bl[0], ac0); ac1 = MFMA_B16(a0, bl[1], ac1);
        ac0 = MFMA_B16(a1, bl[2], ac0); ac1 = MFMA_B16(a1, bl[3], ac1);
        ac0 = MFMA_B16(a2, bl[4], ac0); ac1 = MFMA_B16(a2, bl[5], ac1);
        ac0 = MFMA_B16(a3, bl[6], ac0); ac1 = MFMA_B16(a3, bl[7], ac1);
        #pragma unroll
        for (int r = 0; r < 4; r++) {
            float* Tw = T + (tb + r) * 36 + lr;
            Tw[0] = ac0[r]; Tw[16] = ac1[r];
        }
        __syncthreads();
        {
            const int e  = te + eE;
            const int rr = row[e], cc = col[e];
            const float* Tp = T + eE * 36 + q * 8;
            const bf16* ap = A3b + (size_t)rr * 32 + q * 8;
            const bf16* bp = B3b + (size_t)cc * 32 + q * 8;
            const float* cp = c0s + q * 8;
            float4 hv0 = relu4s(*(const float4*)(Tp + 0), ld_bf4(ap + 0), ld_bf4(bp + 0), cp + 0);
            float4 hv1 = relu4s(*(const float4*)(Tp + 4), ld_bf4(ap + 4), ld_bf4(bp + 4), cp + 4);
            st_bf8(h3 + (size_t)e * 32 + q * 8, hv0, hv1);
        }
        __syncthreads();
    }
}

// node-gather pool sums of h3 (32 ch) + layer-3 stats; 4 lanes/node; unroll x2.
__global__ __launch_bounds__(256) void k_gsp(const bf16* __restrict__ h3,
                                             const int* __restrict__ bucket,
                                             const int* __restrict__ off,
                                             float* __restrict__ pool,
                                             float* __restrict__ Ssum, float* __restrict__ S2sum) {
    __shared__ float red[64];
    if (threadIdx.x < 64) red[threadIdx.x] = 0.f;
    __syncthreads();
    int g = blockIdx.x * 64 + (threadIdx.x >> 2);   // grid ceil(NE/64)
    int q = threadIdx.x & 3;
    float4 aa = {0,0,0,0}, ab = {0,0,0,0}, sa = {0,0,0,0}, sb = {0,0,0,0};
    int e0 = 0, e1 = 0;
    if (g < NE) { e0 = off[g]; e1 = off[g + 1]; }
    const bf16* hk = h3 + q * 8;
    {
        int idx = e0;
        for (; idx + 1 < e1; idx += 2) {
            int i0 = bucket[idx], i1 = bucket[idx + 1];
            float4 aL, aH, cL, cH;
            ld_bf8v(hk + (size_t)i0 * 32, aL, aH);
            ld_bf8v(hk + (size_t)i1 * 32, cL, cH);
            ADD4(aa, aL); ADD4(ab, aH); ADD4(aa, cL); ADD4(ab, cH);
            SQ4(sa, aL); SQ4(sb, aH); SQ4(sa, cL); SQ4(sb, cH);
        }
        if (idx < e1) {
            int i = bucket[idx];
            float4 aL, aH;
            ld_bf8v(hk + (size_t)i * 32, aL, aH);
            ADD4(aa, aL); ADD4(ab, aH);
            SQ4(sa, aL); SQ4(sb, aH);
        }
    }
    if (g < NE) {
        *(float4*)(pool + (size_t)g * 32 + q * 8) = aa;
        *(float4*)(pool + (size_t)g * 32 + q * 8 + 4) = ab;
    }
    {
        int o = q * 8;
        atomicAdd(&red[o+0], aa.x); atomicAdd(&red[o+1], aa.y);
        atomicAdd(&red[o+2], aa.z); atomicAdd(&red[o+3], aa.w);
        atomicAdd(&red[o+4], ab.x); atomicAdd(&red[o+5], ab.y);
        atomicAdd(&red[o+6], ab.z); atomicAdd(&red[o+7], ab.w);
        atomicAdd(&red[32+o+0], sa.x); atomicAdd(&red[32+o+1], sa.y);
        atomicAdd(&red[32+o+2], sa.z); atomicAdd(&red[32+o+3], sa.w);
        atomicAdd(&red[32+o+4], sb.x); atomicAdd(&red[32+o+5], sb.y);
        atomicAdd(&red[32+o+6], sb.z); atomicAdd(&red[32+o+7], sb.w);
    }
    __syncthreads();
    if (threadIdx.x < 32) {
        unsafeAtomicAdd(&Ssum[threadIdx.x], red[threadIdx.x]);
        unsafeAtomicAdd(&S2sum[threadIdx.x], red[32 + threadIdx.x]);
    }
}

// ==================== legacy fast-path compute kernels (fallback if ws too small) ====================

__global__ __launch_bounds__(256) void k_gsh2(const bf16* __restrict__ h1,
                                              const int* __restrict__ bucket,
                                              const int* __restrict__ off,
                                              const int* __restrict__ perm,
                                              const int* __restrict__ col,
                                              const float* __restrict__ Wb,
                                              const float* __restrict__ mp1,
                                              const float* __restrict__ c02,
                                              const bf16* __restrict__ A2b, const bf16* __restrict__ B2b,
                                              float* __restrict__ rawR, float* __restrict__ rawC,
                                              float* __restrict__ Ssum, float* __restrict__ S2sum) {
    __shared__ __align__(16) float W20s[2048], W21s[2048];
    __shared__ __align__(16) float nm1s[32], rs1s[32], c02s[64];
    __shared__ float red[128];
    for (int i = threadIdx.x; i < 2048; i += 256) {
        W20s[i] = Wb[W2O + i];
        W21s[i] = Wb[W2O + 2048 + i];
    }
    if (threadIdx.x < 32) {
        float m = mp1[threadIdx.x], rr = mp1[64 + threadIdx.x];
        nm1s[threadIdx.x] = -m * rr; rs1s[threadIdx.x] = rr;
    }
    if (threadIdx.x < 64) c02s[threadIdx.x] = c02[threadIdx.x];
    if (threadIdx.x < 128) red[threadIdx.x] = 0.f;
    __syncthreads();
    const int g    = blockIdx.x * 16 + (threadIdx.x >> 4);   // grid exactly NE/16
    const int lane = threadIdx.x & 15;
    const int gb   = (threadIdx.x & 63) & ~15;
    const int myo  = lane * 4;
    float4 a2n = ld_bf4(A2b + (size_t)g * 64 + myo);
    float4 b2n = ld_bf4(B2b + (size_t)g * 64 + myo);
    float4 cc  = *(const float4*)(c02s + myo);
    float rA = rs1s[lane*2], rB = rs1s[lane*2+1];
    float nA = nm1s[lane*2], nB = nm1s[lane*2+1];
    float4 racc = {0,0,0,0}, cacc = {0,0,0,0}, st1 = {0,0,0,0}, st2 = {0,0,0,0};
    int e0 = off[g], e1 = off[g + 1];
    for (int idx = e0; idx < e1; idx++) {
        int i = bucket[idx], p = perm[i], c = col[i];
        float2 hi2 = ld_bf2(h1 + (size_t)i * 32 + lane * 2);
        float2 hp2 = ld_bf2(h1 + (size_t)p * 32 + lane * 2);
        float xi0 = hi2.x * rA + nA, xi1 = hi2.y * rB + nB;
        float xp0 = hp2.x * rA + nA, xp1 = hp2.y * rB + nB;
        float4 a2c = ld_bf4(A2b + (size_t)c * 64 + myo);
        float4 b2c = ld_bf4(B2b + (size_t)c * 64 + myo);
        float4 ai, ap;
        ai.x = cc.x + a2n.x + b2c.x; ai.y = cc.y + a2n.y + b2c.y;
        ai.z = cc.z + a2n.z + b2c.z; ai.w = cc.w + a2n.w + b2c.w;
        ap.x = cc.x + a2c.x + b2n.x; ap.y = cc.y + a2c.y + b2n.y;
        ap.z = cc.z + a2c.z + b2n.z; ap.w = cc.w + a2c.w + b2n.w;
        #pragma unroll
        for (int s = 0; s < 16; s++) {
            float va0 = __shfl(xi0, gb + s, 64), va1 = __shfl(xi1, gb + s, 64);
            float vb0 = __shfl(xp0, gb + s, 64), vb1 = __shfl(xp1, gb + s, 64);
            float4 W0a = *(const float4*)(W20s + (2*s)   * 64 + myo);
            float4 W0b = *(const float4*)(W20s + (2*s+1) * 64 + myo);
            float4 W1a = *(const float4*)(W21s + (2*s)   * 64 + myo);
            float4 W1b = *(const float4*)(W21s + (2*s+1) * 64 + myo);
            FMA4S(ai, va0, W0a); FMA4S(ai, va1, W0b);
            FMA4S(ai, vb0, W1a); FMA4S(ai, vb1, W1b);
            FMA4S(ap, vb0, W0a); FMA4S(ap, vb1, W0b);
            FMA4S(ap, va0, W1a); FMA4S(ap, va1, W1b);
        }
        float4 h2i, h2p;
        h2i.x=fmaxf(ai.x,0.f); h2i.y=fmaxf(ai.y,0.f); h2i.z=fmaxf(ai.z,0.f); h2i.w=fmaxf(ai.w,0.f);
        h2p.x=fmaxf(ap.x,0.f); h2p.y=fmaxf(ap.y,0.f); h2p.z=fmaxf(ap.z,0.f); h2p.w=fmaxf(ap.w,0.f);
        ADD4(racc, h2i); ADD4(cacc, h2p); ADD4(st1, h2i);
        st2.x += h2i.x*h2i.x; st2.y += h2i.y*h2i.y; st2.z += h2i.z*h2i.z; st2.w += h2i.w*h2i.w;
    }
    *(float4*)(rawR + (size_t)g * 64 + myo) = racc;
    *(float4*)(rawC + (size_t)g * 64 + myo) = cacc;
    atomicAdd(&red[myo+0], st1.x); atomicAdd(&red[myo+1], st1.y);
    atomicAdd(&red[myo+2], st1.z); atomicAdd(&red[myo+3], st1.w);
    atomicAdd(&red[64+myo+0], st2.x); atomicAdd(&red[64+myo+1], st2.y);
    atomicAdd(&red[64+myo+2], st2.z); atomicAdd(&red[64+myo+3], st2.w);
    __syncthreads();
    if (threadIdx.x < 64) {
        unsafeAtomicAdd(&Ssum[threadIdx.x], red[threadIdx.x]);
        unsafeAtomicAdd(&S2sum[threadIdx.x], red[64 + threadIdx.x]);
    }
}

__global__ __launch_bounds__(256) void k_l3n(const bf16* __restrict__ h1,
                                             const int* __restrict__ bucket,
                                             const int* __restrict__ off,
                                             const int* __restrict__ perm,
                                             const int* __restrict__ col,
                                             const float* __restrict__ Wb,
                                             const float* __restrict__ mp1,
                                             const float* __restrict__ c02,
                                             const bf16* __restrict__ A2b, const bf16* __restrict__ B2b,
                                             const float* __restrict__ mp2,
                                             const float* __restrict__ c03,
                                             const bf16* __restrict__ A3b, const bf16* __restrict__ B3b,
                                             float* __restrict__ pool,
                                             float* __restrict__ Ssum, float* __restrict__ S2sum) {
    __shared__ __align__(16) float W20s[2048], W21s[2048], W30s[2048], W31s[2048];
    __shared__ __align__(16) float nm1s[32], rs1s[32], nm2s[64], rs2s[64], c02s[64], c03s[32];
    __shared__ float red[64];
    for (int i = threadIdx.x; i < 2048; i += 256) {
        W20s[i] = Wb[W2O + i];
        W21s[i] = Wb[W2O + 2048 + i];
        W30s[i] = Wb[W3O + i];
        W31s[i] = Wb[W3O + 2048 + i];
    }
    if (threadIdx.x < 32) {
        float m = mp1[threadIdx.x], rr = mp1[64 + threadIdx.x];
        nm1s[threadIdx.x] = -m * rr; rs1s[threadIdx.x] = rr;
        c03s[threadIdx.x] = c03[threadIdx.x];
    }
    if (threadIdx.x < 64) {
        float m = mp2[threadIdx.x], rr = mp2[64 + threadIdx.x];
        nm2s[threadIdx.x] = -m * rr; rs2s[threadIdx.x] = rr;
        c02s[threadIdx.x] = c02[threadIdx.x];
        red[threadIdx.x] = 0.f;
    }
    __syncthreads();
    const int g    = blockIdx.x * 16 + (threadIdx.x >> 4);   // grid exactly NE/16
    const int lane = threadIdx.x & 15;
    const int gb   = (threadIdx.x & 63) & ~15;
    const int myo  = lane * 4;
    const int myo3 = lane * 2;
    float4 a2n = ld_bf4(A2b + (size_t)g * 64 + myo);
    float4 b2n = ld_bf4(B2b + (size_t)g * 64 + myo);
    float4 cc  = *(const float4*)(c02s + myo);
    float2 a3n = ld_bf2(A3b + (size_t)g * 32 + myo3);
    float rA = rs1s[lane*2], rB = rs1s[lane*2+1];
    float nA = nm1s[lane*2], nB = nm1s[lane*2+1];
    float rs20 = rs2s[myo+0], rs21 = rs2s[myo+1], rs22 = rs2s[myo+2], rs23 = rs2s[myo+3];
    float nm20 = nm2s[myo+0], nm21 = nm2s[myo+1], nm22 = nm2s[myo+2], nm23 = nm2s[myo+3];
    float2 pacc = {0,0}, st1 = {0,0}, st2 = {0,0};
    int e0 = off[g], e1 = off[g + 1];
    for (int idx = e0; idx < e1; idx++) {
        int i = bucket[idx], p = perm[i], c = col[i];
        float2 hi2 = ld_bf2(h1 + (size_t)i * 32 + lane * 2);
        float2 hp2 = ld_bf2(h1 + (size_t)p * 32 + lane * 2);
        float xi0 = hi2.x * rA + nA, xi1 = hi2.y * rB + nB;
        float xp0 = hp2.x * rA + nA, xp1 = hp2.y * rB + nB;
        float4 a2c = ld_bf4(A2b + (size_t)c * 64 + myo);
        float4 b2c = ld_bf4(B2b + (size_t)c * 64 + myo);
        float4 ai, ap;
        ai.x = cc.x + a2n.x + b2c.x; ai.y = cc.y + a2n.y + b2c.y;
        ai.z = cc.z + a2n.z + b2c.z; ai.w = cc.w + a2n.w + b2c.w;
        ap.x = cc.x + a2c.x + b2n.x; ap.y = cc.y + a2c.y + b2n.y;
        ap.z = cc.z + a2c.z + b2n.z; ap.w = cc.w + a2c.w + b2n.w;
        #pragma unroll
        for (int s = 0; s < 16; s++) {
            float va0 = __shfl(xi0, gb + s, 64), va1 = __shfl(xi1, gb + s, 64);
            float vb0 = __shfl(xp0, gb + s, 64), vb1 = __shfl(xp1, gb + s, 64);
            float4 W0a = *(const float4*)(W20s + (2*s)   * 64 + myo);
            float4 W0b = *(const float4*)(W20s + (2*s+1) * 64 + myo);
            float4 W1a = *(const float4*)(W21s + (2*s)   * 64 + myo);
            float4 W1b = *(const float4*)(W21s + (2*s+1) * 64 + myo);
            FMA4S(ai, va0, W0a); FMA4S(ai, va1, W0b);
            FMA4S(ai, vb0, W1a); FMA4S(ai, vb1, W1b);
            FMA4S(ap, vb0, W0a); FMA4S(ap, vb1, W0b);
            FMA4S(ap, va0, W1a); FMA4S(ap, va1, W1b);
        }
        float he0 = fmaxf(ai.x,0.f)*rs20+nm20, he1 = fmaxf(ai.y,0.f)*rs21+nm21;
        float he2 = fmaxf(ai.z,0.f)*rs22+nm22, he3 = fmaxf(ai.w,0.f)*rs23+nm23;
        float hq0 = fmaxf(ap.x,0.f)*rs20+nm20, hq1 = fmaxf(ap.y,0.f)*rs21+nm21;
        float hq2 = fmaxf(ap.z,0.f)*rs22+nm22, hq3 = fmaxf(ap.w,0.f)*rs23+nm23;
        float2 b3c = ld_bf2(B3b + (size_t)c * 32 + myo3);
        float a30 = a3n.x + b3c.x + c03s[myo3];
        float a31 = a3n.y + b3c.y + c03s[myo3 + 1];
        #pragma unroll
        for (int s = 0; s < 16; s++) {
            float e0v = __shfl(he0, gb+s, 64), e1v = __shfl(he1, gb+s, 64);
            float e2v = __shfl(he2, gb+s, 64), e3v = __shfl(he3, gb+s, 64);
            float q0v = __shfl(hq0, gb+s, 64), q1v = __shfl(hq1, gb+s, 64);
            float q2v = __shfl(hq2, gb+s, 64), q3v = __shfl(hq3, gb+s, 64);
            const float* w30 = W30s + (4*s) * 32 + myo3;
            const float* w31 = W31s + (4*s) * 32 + myo3;
            a30 += e0v*w30[0]    + q0v*w31[0];
            a31 += e0v*w30[1]    + q0v*w31[1];
            a30 += e1v*w30[32]   + q1v*w31[32];
            a31 += e1v*w30[33]   + q1v*w31[33];
            a30 += e2v*w30[64]   + q2v*w31[64];
            a31 += e2v*w30[65]   + q2v*w31[65];
            a30 += e3v*w30[96]   + q3v*w31[96];
            a31 += e3v*w30[97]   + q3v*w31[97];
        }
        float h30 = fmaxf(a30, 0.f), h31 = fmaxf(a31, 0.f);
        pacc.x += h30; pacc.y += h31;
        st1.x += h30; st1.y += h31;
        st2.x += h30 * h30; st2.y += h31 * h31;
    }
    *(float2*)(pool + (size_t)g * 32 + myo3) = pacc;
    atomicAdd(&red[myo3], st1.x); atomicAdd(&red[myo3 + 1], st1.y);
    atomicAdd(&red[32 + myo3], st2.x); atomicAdd(&red[32 + myo3 + 1], st2.y);
    __syncthreads();
    if (threadIdx.x < 32) {
        unsafeAtomicAdd(&Ssum[threadIdx.x], red[threadIdx.x]);
        unsafeAtomicAdd(&S2sum[threadIdx.x], red[32 + threadIdx.x]);
    }
}

// ==================== FALLBACK PATH (R4, atomic seg sums) ====================

__global__ __launch_bounds__(256) void k_seg1(const void* __restrict__ xv,
                                              const int* __restrict__ dflag,
                                              const int* __restrict__ row,
                                              const int* __restrict__ col,
                                              float* __restrict__ rsum, float* __restrict__ csum) {
    int flag = dflag[0];
    int t = blockIdx.x * 256 + threadIdx.x;
    int e = t >> 2, q = t & 3;
    float4 xvv = fin4(ld_x4(xv, flag, (size_t)t));
    float* rp = rsum + (size_t)row[e] * 64 + q * 4;
    float* cp = csum + (size_t)col[e] * 64 + q * 4;
    unsafeAtomicAdd(rp + 0, xvv.x); unsafeAtomicAdd(rp + 1, xvv.y);
    unsafeAtomicAdd(rp + 2, xvv.z); unsafeAtomicAdd(rp + 3, xvv.w);
    unsafeAtomicAdd(cp + 0, xvv.x); unsafeAtomicAdd(cp + 1, xvv.y);
    unsafeAtomicAdd(cp + 2, xvv.z); unsafeAtomicAdd(cp + 3, xvv.w);
}

template<int CIN, int COUT, int OST>
__global__ __launch_bounds__(256) void k_node(const float* __restrict__ inR,
                                              const float* __restrict__ inC,
                                              const float* __restrict__ invc,
                                              const float* __restrict__ mp,
                                              const float* __restrict__ W,
                                              float* __restrict__ outA, float* __restrict__ outB) {
    constexpr int QC = COUT / 4;
    constexpr int G  = 256 / QC;
    __shared__ __align__(16) float W2s[CIN*COUT], W3s[CIN*COUT], W4s[CIN*COUT], W5s[CIN*COUT];
    __shared__ __align__(16) float rmS[G*CIN], cmS[G*CIN];
    for (int i = threadIdx.x; i < CIN * COUT; i += 256) {
        W2s[i] = W[2 * CIN * COUT + i];
        W3s[i] = W[3 * CIN * COUT + i];
        W4s[i] = W[4 * CIN * COUT + i];
        W5s[i] = W[5 * CIN * COUT + i];
    }
    int n0 = blockIdx.x * G;
    for (int i = threadIdx.x; i < G * CIN; i += 256) {
        int g = i / CIN, ci = i % CIN;
        int n = n0 + g;
        float ic = invc[n];
        float m = mp[ci], rs = mp[64 + ci];
        rmS[i] = (inR[(size_t)n * 64 + ci] * ic - m) * rs;
        cmS[i] = (inC[(size_t)n * 64 + ci] * ic - m) * rs;
    }
    __syncthreads();
    int g = threadIdx.x / QC, q = threadIdx.x % QC;
    int n = n0 + g;
    float4 a = {0,0,0,0}, b = {0,0,0,0};
    #pragma unroll 4
    for (int ci = 0; ci < CIN; ci++) {
        float rm = rmS[g * CIN + ci], cm = cmS[g * CIN + ci];
        float4 w2 = *(const float4*)(W2s + ci * COUT + q * 4);
        float4 w3 = *(const float4*)(W3s + ci * COUT + q * 4);
        float4 w4 = *(const float4*)(W4s + ci * COUT + q * 4);
        float4 w5 = *(const float4*)(W5s + ci * COUT + q * 4);
        FMA4S(a, rm, w2); FMA4S(a, cm, w4);
        FMA4S(b, rm, w3); FMA4S(b, cm, w5);
    }
    *(float4*)(outA + (size_t)n * OST + q * 4) = a;
    *(float4*)(outB + (size_t)n * OST + q * 4) = b;
}

__global__ __launch_bounds__(256) void k_l1(const void* __restrict__ xv,
                                            const int* __restrict__ dflag,
                                            const int* __restrict__ row, const int* __restrict__ col,
                                            const int* __restrict__ perm,
                                            const float* __restrict__ Wb,
                                            const float* __restrict__ c01,
                                            const float* __restrict__ A1, const float* __restrict__ B1,
                                            float* __restrict__ segR, float* __restrict__ segC,
                                            float* __restrict__ Ssum, float* __restrict__ S2sum) {
    const int flag = dflag[0];
    __shared__ __align__(16) float W10s[512], W11s[512];
    __shared__ __align__(16) float c01s[32];
    __shared__ float red[64];
    for (int i = threadIdx.x; i < 512; i += 256) {
        W10s[i] = Wb[W1O + i];
        W11s[i] = Wb[W1O + 512 + i];
    }
    if (threadIdx.x < 32) c01s[threadIdx.x] = c01[threadIdx.x];
    if (threadIdx.x < 64) red[threadIdx.x] = 0.f;
    __syncthreads();
    const int j = threadIdx.x & 3;
    const int o = j * 8;
    float s1[8] = {0,0,0,0,0,0,0,0}, s2[8] = {0,0,0,0,0,0,0,0};
    for (int e = blockIdx.x * 64 + (threadIdx.x >> 2); e < NZ; e += gridDim.x * 64) {
        int r = row[e], c = col[e], p = perm[e];
        float xe[16], xp[16];
        #pragma unroll
        for (int i4 = 0; i4 < 4; i4++) {
            float4 va = fin4(ld_x4(xv, flag, (size_t)e * 4 + i4));
            float4 vb = fin4(ld_x4(xv, flag, (size_t)p * 4 + i4));
            xe[i4*4+0]=va.x; xe[i4*4+1]=va.y; xe[i4*4+2]=va.z; xe[i4*4+3]=va.w;
            xp[i4*4+0]=vb.x; xp[i4*4+1]=vb.y; xp[i4*4+2]=vb.z; xp[i4*4+3]=vb.w;
        }
        float ae[8];
        #pragma unroll
        for (int u2 = 0; u2 < 2; u2++) {
            float4 a1 = *(const float4*)(A1 + (size_t)r * 32 + o + u2 * 4);
            float4 b1 = *(const float4*)(B1 + (size_t)c * 32 + o + u2 * 4);
            float4 ccv = *(const float4*)(c01s + o + u2 * 4);
            ae[u2*4+0]=ccv.x+a1.x+b1.x; ae[u2*4+1]=ccv.y+a1.y+b1.y;
            ae[u2*4+2]=ccv.z+a1.z+b1.z; ae[u2*4+3]=ccv.w+a1.w+b1.w;
        }
        #pragma unroll
        for (int ci = 0; ci < 16; ci++) {
            const float* w0 = W10s + ci * 32 + o;
            const float* w1 = W11s + ci * 32 + o;
            float a = xe[ci], b = xp[ci];
            #pragma unroll
            for (int u = 0; u < 8; u++) ae[u] += a * w0[u] + b * w1[u];
        }
        float* rp = segR + (size_t)r * 64 + o;
        float* cp = segC + (size_t)c * 64 + o;
        #pragma unroll
        for (int u = 0; u < 8; u++) {
            float h = fmaxf(ae[u], 0.f);
            s1[u] += h; s2[u] += h * h;
            unsafeAtomicAdd(rp + u, h);
            unsafeAtomicAdd(cp + u, h);
        }
    }
    #pragma unroll
    for (int u = 0; u < 8; u++) {
        atomicAdd(&red[o + u], s1[u]);
        atomicAdd(&red[32 + o + u], s2[u]);
    }
    __syncthreads();
    if (threadIdx.x < 32) {
        unsafeAtomicAdd(&Ssum[threadIdx.x], red[threadIdx.x]);
        unsafeAtomicAdd(&S2sum[threadIdx.x], red[32 + threadIdx.x]);
    }
}

template<bool FINAL>
__global__ __launch_bounds__(256) void k_pair(const void* __restrict__ xv,
                                              const int* __restrict__ dflag,
                                              const int* __restrict__ row, const int* __restrict__ col,
                                              const int* __restrict__ perm,
                                              const float* __restrict__ Wb,
                                              const float* __restrict__ c01,
                                              const float* __restrict__ A1, const float* __restrict__ B1,
                                              const float* __restrict__ mp1,
                                              const float* __restrict__ c02,
                                              const float* __restrict__ A2, const float* __restrict__ B2,
                                              const float* __restrict__ mp2,
                                              const float* __restrict__ c03,
                                              const float* __restrict__ A3, const float* __restrict__ B3,
                                              float* __restrict__ segR, float* __restrict__ segC,
                                              float* __restrict__ Ssum, float* __restrict__ S2sum) {
    const int flag = dflag[0];
    constexpr int NCH = FINAL ? 32 : 64;
    __shared__ __align__(16) float W10s[512], W11s[512];
    __shared__ __align__(16) float W20s[2048], W21s[2048];
    __shared__ __align__(16) float W30s[2048], W31s[2048];
    __shared__ __align__(16) float c01s[32], nm1s[32], rs1s[32];
    __shared__ __align__(16) float c02s[64], nm2s[64], rs2s[64], c03s[32];
    __shared__ float red[2 * NCH];
    for (int i = threadIdx.x; i < 512; i += 256) {
        W10s[i] = Wb[W1O + i];
        W11s[i] = Wb[W1O + 512 + i];
    }
    for (int i = threadIdx.x; i < 2048; i += 256) {
        W20s[i] = Wb[W2O + i];
        W21s[i] = Wb[W2O + 2048 + i];
        if (FINAL) {
            W30s[i] = Wb[W3O + i];
            W31s[i] = Wb[W3O + 2048 + i];
        }
    }
    if (threadIdx.x < 32) {
        c01s[threadIdx.x] = c01[threadIdx.x];
        float m = mp1[threadIdx.x], rr = mp1[64 + threadIdx.x];
        nm1s[threadIdx.x] = -m * rr; rs1s[threadIdx.x] = rr;
        if (FINAL) c03s[threadIdx.x] = c03[threadIdx.x];
    }
    if (threadIdx.x < 64) {
        c02s[threadIdx.x] = c02[threadIdx.x];
        if (FINAL) {
            float m = mp2[threadIdx.x], rr = mp2[64 + threadIdx.x];
            nm2s[threadIdx.x] = -m * rr; rs2s[threadIdx.x] = rr;
        }
    }
    if (threadIdx.x < 2 * NCH) red[threadIdx.x] = 0.f;
    __syncthreads();
    const int j  = threadIdx.x & 3;
    const int qb = (threadIdx.x & 63) & ~3;
    constexpr int LCH = FINAL ? 8 : 16;
    float s1[LCH], s2[LCH];
    #pragma unroll
    for (int k = 0; k < LCH; k++) { s1[k] = 0.f; s2[k] = 0.f; }
    for (int e = blockIdx.x * 64 + (threadIdx.x >> 2); e < NZ; e += gridDim.x * 64) {
        int r = row[e], c = col[e], p = perm[e];
        float xe[16], xp[16];
        #pragma unroll
        for (int i4 = 0; i4 < 4; i4++) {
            float4 va = fin4(ld_x4(xv, flag, (size_t)e * 4 + i4));
            float4 vb = fin4(ld_x4(xv, flag, (size_t)p * 4 + i4));
            xe[i4*4+0]=va.x; xe[i4*4+1]=va.y; xe[i4*4+2]=va.z; xe[i4*4+3]=va.w;
            xp[i4*4+0]=vb.x; xp[i4*4+1]=vb.y; xp[i4*4+2]=vb.z; xp[i4*4+3]=vb.w;
        }
        const int o1 = j * 8;
        float ae[8], ap[8];
        #pragma unroll
        for (int u2 = 0; u2 < 2; u2++) {
            float4 a1r = *(const float4*)(A1 + (size_t)r * 32 + o1 + u2 * 4);
            float4 b1c = *(const float4*)(B1 + (size_t)c * 32 + o1 + u2 * 4);
            float4 a1c = *(const float4*)(A1 + (size_t)c * 32 + o1 + u2 * 4);
            float4 b1r = *(const float4*)(B1 + (size_t)r * 32 + o1 + u2 * 4);
            float4 ccv = *(const float4*)(c01s + o1 + u2 * 4);
            ae[u2*4+0]=ccv.x+a1r.x+b1c.x; ae[u2*4+1]=ccv.y+a1r.y+b1c.y;
            ae[u2*4+2]=ccv.z+a1r.z+b1c.z; ae[u2*4+3]=ccv.w+a1r.w+b1c.w;
            ap[u2*4+0]=ccv.x+a1c.x+b1r.x; ap[u2*4+1]=ccv.y+a1c.y+b1r.y;
            ap[u2*4+2]=ccv.z+a1c.z+b1r.z; ap[u2*4+3]=ccv.w+a1c.w+b1r.w;
        }
        #pragma unroll
        for (int ci = 0; ci < 16; ci++) {
            const float* w0 = W10s + ci * 32 + o1;
            const float* w1 = W11s + ci * 32 + o1;
            float a = xe[ci], b = xp[ci];
            #pragma unroll
            for (int u = 0; u < 8; u++) {
                ae[u] += a * w0[u] + b * w1[u];
                ap[u] += b * w0[u] + a * w1[u];
            }
        }
        #pragma unroll
        for (int u = 0; u < 8; u++) {
            ae[u] = fmaxf(ae[u], 0.f) * rs1s[o1 + u] + nm1s[o1 + u];
            ap[u] = fmaxf(ap[u], 0.f) * rs1s[o1 + u] + nm1s[o1 + u];
        }
        const int o2 = j * 16;
        float be[16], bp[16];
        #pragma unroll
        for (int t4 = 0; t4 < 4; t4++) {
            float4 a2r = *(const float4*)(A2 + (size_t)r * 64 + o2 + t4 * 4);
            float4 b2c = *(const float4*)(B2 + (size_t)c * 64 + o2 + t4 * 4);
            float4 ccv = *(const float4*)(c02s + o2 + t4 * 4);
            be[t4*4+0]=ccv.x+a2r.x+b2c.x; be[t4*4+1]=ccv.y+a2r.y+b2c.y;
            be[t4*4+2]=ccv.z+a2r.z+b2c.z; be[t4*4+3]=ccv.w+a2r.w+b2c.w;
            if (FINAL) {
                float4 a2c = *(const float4*)(A2 + (size_t)c * 64 + o2 + t4 * 4);
                float4 b2r = *(const float4*)(B2 + (size_t)r * 64 + o2 + t4 * 4);
                bp[t4*4+0]=ccv.x+a2c.x+b2r.x; bp[t4*4+1]=ccv.y+a2c.y+b2r.y;
                bp[t4*4+2]=ccv.z+a2c.z+b2r.z; bp[t4*4+3]=ccv.w+a2c.w+b2r.w;
            }
        }
        #pragma unroll
        for (int l = 0; l < 4; l++) {
            #pragma unroll
            for (int u = 0; u < 8; u++) {
                float a = __shfl(ae[u], qb + l, 64);
                float b = __shfl(ap[u], qb + l, 64);
                const float* w0 = W20s + (l * 8 + u) * 64 + o2;
                const float* w1 = W21s + (l * 8 + u) * 64 + o2;
                #pragma unroll
                for (int t = 0; t < 16; t++) {
                    be[t] += a * w0[t] + b * w1[t];
                    if (FINAL) bp[t] += b * w0[t] + a * w1[t];
                }
            }
        }
        if (!FINAL) {
            float* rp = segR + (size_t)r * 64 + o2;
            float* cp = segC + (size_t)c * 64 + o2;
            #pragma unroll
            for (int t = 0; t < 16; t++) {
                float h = fmaxf(be[t], 0.f);
                s1[t] += h; s2[t] += h * h;
                unsafeAtomicAdd(rp + t, h);
                unsafeAtomicAdd(cp + t, h);
            }
        } else {
            #pragma unroll
            for (int t = 0; t < 16; t++) {
                be[t] = fmaxf(be[t], 0.f) * rs2s[o2 + t] + nm2s[o2 + t];
                bp[t] = fmaxf(bp[t], 0.f) * rs2s[o2 + t] + nm2s[o2 + t];
            }
            float a3[8];
            #pragma unroll
            for (int u2 = 0; u2 < 2; u2++) {
                float4 a3r = *(const float4*)(A3 + (size_t)r * 32 + o1 + u2 * 4);
                float4 b3c = *(const float4*)(B3 + (size_t)c * 32 + o1 + u2 * 4);
                float4 ccv = *(const float4*)(c03s + o1 + u2 * 4);
                a3[u2*4+0]=ccv.x+a3r.x+b3c.x; a3[u2*4+1]=ccv.y+a3r.y+b3c.y;
                a3[u2*4+2]=ccv.z+a3r.z+b3c.z; a3[u2*4+3]=ccv.w+a3r.w+b3c.w;
            }
            #pragma unroll
            for (int l = 0; l < 4; l++) {
                #pragma unroll
                for (int t = 0; t < 16; t++) {
                    float a = __shfl(be[t], qb + l, 64);
                    float b = __shfl(bp[t], qb + l, 64);
                    const float* w0 = W30s + (l * 16 + t) * 32 + o1;
                    const float* w1 = W31s + (l * 16 + t) * 32 + o1;
                    #pragma unroll
                    for (int u = 0; u < 8; u++)
                        a3[u] += a * w0[u] + b * w1[u];
                }
            }
            float* pp = segR + (size_t)r * 32 + o1;
            #pragma unroll
            for (int u = 0; u < 8; u++) {
                float h = fmaxf(a3[u], 0.f);
                s1[u] += h; s2[u] += h * h;
                unsafeAtomicAdd(pp + u, h);
            }
        }
    }
    {
        const int ob = FINAL ? (j * 8) : (j * 16);
        #pragma unroll
        for (int k = 0; k < LCH; k++) {
            atomicAdd(&red[ob + k], s1[k]);
            atomicAdd(&red[NCH + ob + k], s2[k]);
        }
    }
    __syncthreads();
    if (threadIdx.x < NCH) {
        unsafeAtomicAdd(&Ssum[threadIdx.x], red[threadIdx.x]);
        unsafeAtomicAdd(&S2sum[threadIdx.x], red[NCH + threadIdx.x]);
    }
}

// ---------- host ----------
extern "C" void kernel_launch(void* const* d_in, const int* in_sizes, int n_in,
                              void* d_out, int out_size, void* d_ws, size_t ws_size,
                              hipStream_t stream) {
    const void* values = d_in[0];
    const int* row  = (const int*)d_in[1];
    const int* col  = (const int*)d_in[2];
    const int* perm = (const int*)d_in[3];

    char* p = (char*)d_ws;
    auto carve = [&](size_t bytes) { char* r = p; p += (bytes + 255) & ~(size_t)255; return r; };

    // ---------- fast2 (MFMA) carve, ~406 MB ----------
    bf16* h1     = (bf16*)carve((size_t)NZ * 32 * 2);     // 102.4 MB (h3 aliases later)
    bf16* h2     = (bf16*)carve((size_t)NZ * 64 * 2);     // 204.8 MB
    int*  bucket = (int*)carve((size_t)NZ * 4);           // 6.4 MB
    int*  off    = (int*)carve((size_t)(NE + 1) * 4);
    int*  tmp    = (int*)carve((size_t)NE * 4);
    int*  sblk   = (int*)carve(256 * 4);                  // scan block sums + offsets
    float* rawR  = (float*)carve((size_t)NE * 64 * 4);    // 25.6 MB (pool aliases)
    float* rawC  = (float*)carve((size_t)NE * 64 * 4);    // 25.6 MB
    bf16* A2b    = (bf16*)carve((size_t)NE * 64 * 2);     // 12.8 MB
    bf16* B2b    = (bf16*)carve((size_t)NE * 64 * 2);
    bf16* Qa     = (bf16*)carve((size_t)NE * 32 * 2);     // A1 then A3
    bf16* Qb     = (bf16*)carve((size_t)NE * 32 * 2);     // B1 then B3
    bf16* W1fs   = (bf16*)carve(8192 * 2);                // hi+lo folded W1 frags
    bf16* W2fs   = (bf16*)carve(8192 * 2);                // hi+lo folded W2 frags
    bf16* W3fs   = (bf16*)carve(8192 * 2);                // hi+lo folded W3 frags
    int*   cnt   = (int*)carve((size_t)NE * 4);
    float* invc  = (float*)carve((size_t)NE * 4);
    float* Wbuf  = (float*)carve((size_t)WTOT * 4);
    float* misc  = (float*)carve(2048 * 4);
    int*   dflag = (int*)carve(64 * 4);
    size_t need_fast2 = (size_t)(p - (char*)d_ws);
    // misc (floats): mp0@0, mp1@128, mp2@256, mp3@384 (m@+0, rs@+64)
    //   S@512/576/640, S2@768/832/896, tmsum@960, c0@1024/1088/1152,
    //   Wf2@1280, base@1792, corr@1808, c02f@1856, c03f@1920, c01f@1984

    if (ws_size >= need_fast2) {
        bf16* h3 = h1;          // h1 dead after k_l2e
        float* pool = rawR;     // rawR dead after k_nodeb<64,32>
        hipMemsetAsync(misc, 0, 2048 * 4, stream);
        hipMemsetAsync(cnt, 0, (size_t)NE * 4, stream);
        hipMemsetAsync(tmp, 0, (size_t)NE * 4, stream);
        k_detect<<<1, 64, 0, stream>>>((const unsigned*)values, dflag);
        k_convW<<<(WTOT + 255) / 256, 256, 0, stream>>>(d_in[4], d_in[5], d_in[6], d_in[7],
                                                        d_in[8], d_in[9], d_in[10], d_in[11],
                                                        d_in[12], d_in[13], dflag, Wbuf);
        k_prep<<<1, 64, 0, stream>>>(misc);
        k_count<<<NZ / 256, 256, 0, stream>>>(row, cnt);
        k_invcnt<<<(NE + 255) / 256, 256, 0, stream>>>(cnt, invc);
        k_scan1<<<NSB, 1024, 0, stream>>>(cnt, sblk);
        k_scan2<<<1, 128, 0, stream>>>(sblk, sblk + 128, off);
        k_scan3<<<NSB, 1024, 0, stream>>>(cnt, sblk + 128, off);
        k_scatter<<<NZ / 256, 256, 0, stream>>>(row, perm, off, tmp, bucket, dflag);

        // layer 1 (MFMA edge pass; tm folded into gsv)
        k_gsv<<<(NE + 63) / 64, 256, 0, stream>>>(values, dflag, bucket, off, perm,
                                                  rawR, rawC, misc + 960);
        k_nodeb<16, 32><<<NE / 32, 256, 0, stream>>>(rawR, rawC, invc, cnt, misc + 0,
                                                     Wbuf + W1O, Qa, Qb);
        k_const<<<1, 64, 0, stream>>>(Wbuf + W1O, Wbuf + B1O, misc + 960, 1, misc + 1024, 16, 32);
        k_fold<16, 32><<<16, 256, 0, stream>>>(Wbuf + W1O, misc + 0, misc + 1024,
                                               W1fs, misc + 1984);
        k_l1e<<<2500, 256, 0, stream>>>(values, dflag, row, col, perm, W1fs, misc + 1984,
                                        Qa, Qb, h1);
        k_gsh1<true><<<(NE + 63) / 64, 256, 0, stream>>>(h1, bucket, off, perm, dflag,
                                                         rawR, rawC, misc + 512, misc + 768);
        k_fin<<<1, 64, 0, stream>>>(misc + 512, misc + 768, misc + 128, 32);

        // layer 2 (MFMA, materialized h2)
        k_nodeb<32, 64><<<NE / 16, 256, 0, stream>>>(rawR, rawC, invc, cnt, misc + 128,
                                                     Wbuf + W2O, A2b, B2b);
        k_const<<<1, 64, 0, stream>>>(Wbuf + W2O, Wbuf + B2O, misc + 960, 0, misc + 1088, 32, 64);
        k_fold<32, 64><<<16, 256, 0, stream>>>(Wbuf + W2O, misc + 128, misc + 1088,
                                               W2fs, misc + 1856);
        k_l2e<<<2500, 256, 0, stream>>>(h1, row, col, perm, dflag, W2fs, misc + 1856,
                                        A2b, B2b, h2);
        k_gs64<<<NE / 32, 256, 0, stream>>>(h2, bucket, off, perm, dflag, rawR, rawC,
                                            misc + 576, misc + 832);
        k_fin<<<1, 64, 0, stream>>>(misc + 576, misc + 832, misc + 256, 64);

        // layer 3 (MFMA) + pool
        k_nodeb<64, 32><<<NE / 32, 256, 0, stream>>>(rawR, rawC, invc, cnt, misc + 256,
                                                     Wbuf + W3O, Qa, Qb);   // Qa/Qb = A3/B3
        k_const<<<1, 64, 0, stream>>>(Wbuf + W3O, Wbuf + B3O, misc + 960, 0, misc + 1152, 64, 32);
        k_fold<64, 32><<<16, 256, 0, stream>>>(Wbuf + W3O, misc + 256, misc + 1152,
                                               W3fs, misc + 1920);
        k_l3e<<<2500, 256, 0, stream>>>(h2, row, col, perm, dflag, W3fs, misc + 1920,
                                        Qa, Qb, h3);
        k_gsp<<<(NE + 63) / 64, 256, 0, stream>>>(h3, bucket, off, pool, misc + 640, misc + 896);
        k_fin<<<1, 64, 0, stream>>>(misc + 640, misc + 896, misc + 384, 32);

        k_head<<<1, 512, 0, stream>>>(Wbuf, misc + 384, misc + 1280, misc + 1792, misc + 1808);
        k_out<<<NE * 16 / 256, 256, 0, stream>>>(pool, invc, cnt, dflag,
                                                 misc + 1280, misc + 1792, misc + 1808, d_out);
        return;
    }

    // ---------- legacy fast carve (~200 MB) ----------
    p = (char*)d_ws;
    h1     = (bf16*)carve((size_t)NZ * 32 * 2);
    bucket = (int*)carve((size_t)NZ * 4);
    off    = (int*)carve((size_t)(NE + 1) * 4);
    tmp    = (int*)carve((size_t)NE * 4);
    sblk   = (int*)carve(256 * 4);
    rawR   = (float*)carve((size_t)NE * 64 * 4);
    rawC   = (float*)carve((size_t)NE * 64 * 4);
    A2b    = (bf16*)carve((size_t)NE * 64 * 2);
    B2b    = (bf16*)carve((size_t)NE * 64 * 2);
    Qa     = (bf16*)carve((size_t)NE * 32 * 2);
    Qb     = (bf16*)carve((size_t)NE * 32 * 2);
    cnt    = (int*)carve((size_t)NE * 4);
    invc   = (float*)carve((size_t)NE * 4);
    Wbuf   = (float*)carve((size_t)WTOT * 4);
    misc   = (float*)carve(2048 * 4);
    dflag  = (int*)carve(64 * 4);
    size_t need_fast = (size_t)(p - (char*)d_ws);

    if (ws_size >= need_fast) {
        float* pool = rawR;
        hipMemsetAsync(misc, 0, 2048 * 4, stream);
        hipMemsetAsync(cnt, 0, (size_t)NE * 4, stream);
        hipMemsetAsync(tmp, 0, (size_t)NE * 4, stream);
        k_detect<<<1, 64, 0, stream>>>((const unsigned*)values, dflag);
        k_convW<<<(WTOT + 255) / 256, 256, 0, stream>>>(d_in[4], d_in[5], d_in[6], d_in[7],
                                                        d_in[8], d_in[9], d_in[10], d_in[11],
                                                        d_in[12], d_in[13], dflag, Wbuf);
        k_prep<<<1, 64, 0, stream>>>(misc);
        k_count<<<NZ / 256, 256, 0, stream>>>(row, cnt);
        k_invcnt<<<(NE + 255) / 256, 256, 0, stream>>>(cnt, invc);
        k_scan1<<<NSB, 1024, 0, stream>>>(cnt, sblk);
        k_scan2<<<1, 128, 0, stream>>>(sblk, sblk + 128, off);
        k_scan3<<<NSB, 1024, 0, stream>>>(cnt, sblk + 128, off);
        k_scatter<<<NZ / 256, 256, 0, stream>>>(row, perm, off, tmp, bucket, dflag);

        k_gsv<<<(NE + 63) / 64, 256, 0, stream>>>(values, dflag, bucket, off, perm,
                                                  rawR, rawC, misc + 960);
        k_nodeb<16, 32><<<NE / 32, 256, 0, stream>>>(rawR, rawC, invc, cnt, misc + 0,
                                                     Wbuf + W1O, Qa, Qb);
        k_const<<<1, 64, 0, stream>>>(Wbuf + W1O, Wbuf + B1O, misc + 960, 1, misc + 1024, 16, 32);
        k_l1n<<<NZ / 64, 256, 0, stream>>>(values, dflag, row, col, perm, Wbuf, misc + 1024,
                                           Qa, Qb, h1, misc + 512, misc + 768);
        k_fin<<<1, 64, 0, stream>>>(misc + 512, misc + 768, misc + 128, 32);

        k_gsh1<false><<<(NE + 63) / 64, 256, 0, stream>>>(h1, bucket, off, perm, dflag,
                                                          rawR, rawC, nullptr, nullptr);
        k_nodeb<32, 64><<<NE / 16, 256, 0, stream>>>(rawR, rawC, invc, cnt, misc + 128,
                                                     Wbuf + W2O, A2b, B2b);
        k_const<<<1, 64, 0, stream>>>(Wbuf + W2O, Wbuf + B2O, misc + 960, 0, misc + 1088, 32, 64);
        k_gsh2<<<NE / 16, 256, 0, stream>>>(h1, bucket, off, perm, col, Wbuf, misc + 128,
                                            misc + 1088, A2b, B2b, rawR, rawC,
                                            misc + 576, misc + 832);
        k_fin<<<1, 64, 0, stream>>>(misc + 576, misc + 832, misc + 256, 64);

        k_nodeb<64, 32><<<NE / 32, 256, 0, stream>>>(rawR, rawC, invc, cnt, misc + 256,
                                                     Wbuf + W3O, Qa, Qb);
        k_const<<<1, 64, 0, stream>>>(Wbuf + W3O, Wbuf + B3O, misc + 960, 0, misc + 1152, 64, 32);
        k_l3n<<<NE / 16, 256, 0, stream>>>(h1, bucket, off, perm, col, Wbuf, misc + 128,
                                           misc + 1088, A2b, B2b, misc + 256,
                                           misc + 1152, Qa, Qb, pool,
                                           misc + 640, misc + 896);
        k_fin<<<1, 64, 0, stream>>>(misc + 640, misc + 896, misc + 384, 32);

        k_head<<<1, 512, 0, stream>>>(Wbuf, misc + 384, misc + 1280, misc + 1792, misc + 1808);
        k_out<<<NE * 16 / 256, 256, 0, stream>>>(pool, invc, cnt, dflag,
                                                 misc + 1280, misc + 1792, misc + 1808, d_out);
        return;
    }

    // ---------- fallback carve (R4 layout, ~155 MB) ----------
    p = (char*)d_ws;
    float* fR  = (float*)carve((size_t)NE * 64 * 4);
    float* fC  = (float*)carve((size_t)NE * 64 * 4);
    float* A1  = (float*)carve((size_t)NE * 32 * 4);
    float* B1  = (float*)carve((size_t)NE * 32 * 4);
    float* A2  = (float*)carve((size_t)NE * 64 * 4);
    float* B2  = (float*)carve((size_t)NE * 64 * 4);
    float* A3  = (float*)carve((size_t)NE * 32 * 4);
    float* B3  = (float*)carve((size_t)NE * 32 * 4);
    cnt   = (int*)carve((size_t)NE * 4);
    invc  = (float*)carve((size_t)NE * 4);
    Wbuf  = (float*)carve((size_t)WTOT * 4);
    misc  = (float*)carve(2048 * 4);
    dflag = (int*)carve(64 * 4);
    float* fpool = fR;

    hipMemsetAsync(misc, 0, 2048 * 4, stream);
    hipMemsetAsync(cnt, 0, (size_t)NE * 4, stream);
    hipMemsetAsync(fR, 0, (size_t)NE * 64 * 4, stream);
    hipMemsetAsync(fC, 0, (size_t)NE * 64 * 4, stream);
    k_detect<<<1, 64, 0, stream>>>((const unsigned*)values, dflag);
    k_convW<<<(WTOT + 255) / 256, 256, 0, stream>>>(d_in[4], d_in[5], d_in[6], d_in[7],
                                                    d_in[8], d_in[9], d_in[10], d_in[11],
                                                    d_in[12], d_in[13], dflag, Wbuf);
    k_prep<<<1, 64, 0, stream>>>(misc);
    k_count<<<NZ / 256, 256, 0, stream>>>(row, cnt);
    k_invcnt<<<(NE + 255) / 256, 256, 0, stream>>>(cnt, invc);
    k_tm<<<512, 256, 0, stream>>>(values, dflag, misc + 960);

    k_seg1<<<NZ * 4 / 256, 256, 0, stream>>>(values, dflag, row, col, fR, fC);
    k_node<16, 32, 32><<<NE / 32, 256, 0, stream>>>(fR, fC, invc, misc + 0, Wbuf + W1O, A1, B1);
    k_const<<<1, 64, 0, stream>>>(Wbuf + W1O, Wbuf + B1O, misc + 960, 1, misc + 1024, 16, 32);
    hipMemsetAsync(fR, 0, (size_t)NE * 64 * 4, stream);
    hipMemsetAsync(fC, 0, (size_t)NE * 64 * 4, stream);
    k_l1<<<2048, 256, 0, stream>>>(values, dflag, row, col, perm, Wbuf, misc + 1024,
                                   A1, B1, fR, fC, misc + 512, misc + 768);
    k_fin<<<1, 64, 0, stream>>>(misc + 512, misc + 768, misc + 128, 32);

    k_node<32, 64, 64><<<NE / 16, 256, 0, stream>>>(fR, fC, invc, misc + 128, Wbuf + W2O, A2, B2);
    k_const<<<1, 64, 0, stream>>>(Wbuf + W2O, Wbuf + B2O, misc + 960, 0, misc + 1088, 32, 64);
    hipMemsetAsync(fR, 0, (size_t)NE * 64 * 4, stream);
    hipMemsetAsync(fC, 0, (size_t)NE * 64 * 4, stream);
    k_pair<false><<<2048, 256, 0, stream>>>(values, dflag, row, col, perm, Wbuf,
                                            misc + 1024, A1, B1, misc + 128,
                                            misc + 1088, A2, B2, misc + 256,
                                            misc + 1152, A1, B1,
                                            fR, fC, misc + 576, misc + 832);
    k_fin<<<1, 64, 0, stream>>>(misc + 576, misc + 832, misc + 256, 64);

    k_node<64, 32, 32><<<NE / 32, 256, 0, stream>>>(fR, fC, invc, misc + 256, Wbuf + W3O, A3, B3);
    k_const<<<1, 64, 0, stream>>>(Wbuf + W3O, Wbuf + B3O, misc + 960, 0, misc + 1152, 64, 32);
    hipMemsetAsync(fpool, 0, (size_t)NE * 32 * 4, stream);
    k_pair<true><<<2048, 256, 0, stream>>>(values, dflag, row, col, perm, Wbuf,
                                           misc + 1024, A1, B1, misc + 128,
                                           misc + 1088, A2, B2, misc + 256,
                                           misc + 1152, A3, B3,
                                           fpool, nullptr, misc + 640, misc + 896);
    k_fin<<<1, 64, 0, stream>>>(misc + 640, misc + 896, misc + 384, 32);

    k_head<<<1, 512, 0, stream>>>(Wbuf, misc + 384, misc + 1280, misc + 1792, misc + 1808);
    k_out<<<NE * 16 / 256, 256, 0, stream>>>(fpool, invc, cnt, dflag,
                                             misc + 1280, misc + 1792, misc + 1808, d_out);
}